// Round 2
// baseline (2879.293 us; speedup 1.0000x reference)
//
#include <hip/hip_runtime.h>
#include <hip/hip_bf16.h>
#include <math.h>

#define NN 4
#define CC 15
#define HH 320
#define WW 320
#define FF 32
#define KS 11
#define PADN 11
#define CPAD 5
#define HP 342      // HH + 2*PADN
#define NK 31
#define NCB (NN*CC) // 60

// ---------------- K0: centered orthonormal DFT matrix (symmetric) ----------
__global__ void k_dft(float* __restrict__ Fre, float* __restrict__ Fim) {
  int idx = blockIdx.x * blockDim.x + threadIdx.x;
  if (idx >= HH * WW) return;
  int k = idx / WW, n = idx % WW;
  int prod = (k - 160) * (n - 160);
  int r = prod % 320; if (r < 0) r += 320;
  float ang = -6.283185307179586f * (float)r / 320.0f;
  const float s = 0.05590169943749474f; // 1/sqrt(320)
  Fre[idx] = cosf(ang) * s;
  Fim[idx] = sinf(ang) * s;
}

// ---------------- K1: conv (reflect-padded u, zero-padded conv) + RBF ------
__global__ void k_conv_rbf(const float* __restrict__ u_t,
                           const float* __restrict__ ck,
                           const float* __restrict__ w,
                           const float* __restrict__ mu,
                           const float* __restrict__ sigma,
                           float* __restrict__ fuk) {
  __shared__ float kr[KS * KS], ki[KS * KS], wsh[NK], mush[NK];
  int o = blockIdx.z % FF, n = blockIdx.z / FF;
  int t = threadIdx.y * 16 + threadIdx.x;
  if (t < KS * KS) {
    kr[t] = ck[(o * KS * KS + t) * 2 + 0];
    ki[t] = ck[(o * KS * KS + t) * 2 + 1];
  }
  if (t >= 128 && t < 128 + NK) {
    int i = t - 128;
    wsh[i]  = w[o * NK + i];
    mush[i] = mu[i];
  }
  __syncthreads();
  int x = blockIdx.x * 16 + threadIdx.x;
  int y = blockIdx.y * 16 + threadIdx.y;
  if (x >= HP || y >= HP) return;
  float acc = 0.f;
  for (int kyy = 0; kyy < KS; kyy++) {
    int py = y - CPAD + kyy;
    if (py < 0 || py >= HP) continue;
    int ry = py - PADN; if (ry < 0) ry = -ry; if (ry >= HH) ry = 2 * (HH - 1) - ry;
    for (int kxx = 0; kxx < KS; kxx++) {
      int px = x - CPAD + kxx;
      if (px < 0 || px >= HP) continue;
      int rx = px - PADN; if (rx < 0) rx = -rx; if (rx >= WW) rx = 2 * (WW - 1) - rx;
      int ui = ((n * HH + ry) * WW + rx) * 2;
      acc += u_t[ui] * kr[kyy * KS + kxx] + u_t[ui + 1] * ki[kyy * KS + kxx];
    }
  }
  float sg = sigma[0];
  float inv2s2 = 1.0f / (2.0f * sg * sg);
  float r = 0.f;
  for (int i = 0; i < NK; i++) {
    float d = acc - mush[i];
    r += wsh[i] * __expf(-d * d * inv2s2);
  }
  fuk[((n * FF + o) * HP + y) * HP + x] = r;
}

// ---------------- K2: transposed conv (adjoint), crop, /FF -----------------
__global__ void k_convT(const float* __restrict__ fuk,
                        const float* __restrict__ ck,
                        float* __restrict__ Ru) {
  __shared__ float kw[FF][KS * KS][2]; // 30976 B
  __shared__ float tile[26][27];
  int n = blockIdx.z;
  int tid = threadIdx.y * 16 + threadIdx.x;
  for (int idx = tid; idx < FF * KS * KS; idx += 256) {
    int o = idx / (KS * KS), p = idx % (KS * KS);
    kw[o][p][0] = ck[(o * KS * KS + p) * 2 + 0];
    kw[o][p][1] = ck[(o * KS * KS + p) * 2 + 1];
  }
  int y0 = blockIdx.y * 16, x0 = blockIdx.x * 16;
  float ar = 0.f, ai = 0.f;
  for (int o = 0; o < FF; o++) {
    __syncthreads();
    for (int idx = tid; idx < 26 * 26; idx += 256) {
      int ty = idx / 26, tx = idx % 26;
      tile[ty][tx] = fuk[((n * FF + o) * HP + (y0 + 6 + ty)) * HP + (x0 + 6 + tx)];
    }
    __syncthreads();
    for (int kyy = 0; kyy < KS; kyy++)
      for (int kxx = 0; kxx < KS; kxx++) {
        float v = tile[threadIdx.y + 10 - kyy][threadIdx.x + 10 - kxx];
        ar += v * kw[o][kyy * KS + kxx][0];
        ai += v * kw[o][kyy * KS + kxx][1];
      }
  }
  int y = y0 + threadIdx.y, x = x0 + threadIdx.x;
  int oi = ((n * HH + y) * WW + x) * 2;
  Ru[oi]     = ar / (float)FF;
  Ru[oi + 1] = ai / (float)FF;
}

// ---------------- K3: tmp = u * coil_sens (complex) ------------------------
__global__ void k_umul(const float* __restrict__ u_t,
                       const float* __restrict__ cs,
                       float* __restrict__ outA) {
  int idx = blockIdx.x * blockDim.x + threadIdx.x;
  if (idx >= NN * CC * HH * WW) return;
  int hw = idx % (HH * WW);
  int nc = idx / (HH * WW);
  int n = nc / CC;
  float ur = u_t[(n * HH * WW + hw) * 2], ui = u_t[(n * HH * WW + hw) * 2 + 1];
  float cr = cs[idx * 2], ci = cs[idx * 2 + 1];
  outA[idx * 2]     = ur * cr - ui * ci;
  outA[idx * 2 + 1] = ur * ci + ui * cr;
}

// ---------------- tiled complex GEMMs --------------------------------------
#define TB 64
#define KC 16

// C[b] = Fc * X[b]   (Fc symmetric: load Fc[k][i])
__global__ __launch_bounds__(256) void k_gemm_left(
    const float* __restrict__ Fre, const float* __restrict__ Fim,
    const float* __restrict__ Bin, float* __restrict__ Cout, int conjF) {
  __shared__ float Ar[KC][TB + 1], Ai[KC][TB + 1], Br[KC][TB + 1], Bi[KC][TB + 1];
  int b = blockIdx.z;
  int i0 = blockIdx.y * TB, j0 = blockIdx.x * TB;
  int tx = threadIdx.x % 16, ty = threadIdx.x / 16;
  float cr[4][4] = {}, ci[4][4] = {};
  const float* Bb = Bin + (size_t)b * HH * WW * 2;
  float fsign = conjF ? -1.f : 1.f;
  for (int k0 = 0; k0 < WW; k0 += KC) {
    __syncthreads();
    for (int t = threadIdx.x; t < KC * TB; t += 256) {
      int kk = t / TB, ii = t % TB;
      int gi = (k0 + kk) * WW + i0 + ii;
      Ar[kk][ii] = Fre[gi];
      Ai[kk][ii] = fsign * Fim[gi];
      int gj = ((k0 + kk) * WW + j0 + ii) * 2;
      Br[kk][ii] = Bb[gj];
      Bi[kk][ii] = Bb[gj + 1];
    }
    __syncthreads();
    for (int kk = 0; kk < KC; kk++) {
      float arr[4], ari[4], brr[4], bri[4];
      for (int d = 0; d < 4; d++) {
        arr[d] = Ar[kk][ty + 16 * d]; ari[d] = Ai[kk][ty + 16 * d];
        brr[d] = Br[kk][tx + 16 * d]; bri[d] = Bi[kk][tx + 16 * d];
      }
      for (int di = 0; di < 4; di++)
        for (int dj = 0; dj < 4; dj++) {
          cr[di][dj] += arr[di] * brr[dj] - ari[di] * bri[dj];
          ci[di][dj] += arr[di] * bri[dj] + ari[di] * brr[dj];
        }
    }
  }
  for (int di = 0; di < 4; di++)
    for (int dj = 0; dj < 4; dj++) {
      int i = i0 + ty + 16 * di, j = j0 + tx + 16 * dj;
      int oi = (b * HH * WW + i * WW + j) * 2;
      Cout[oi]     = cr[di][dj];
      Cout[oi + 1] = ci[di][dj];
    }
}

// C[b] = X[b] * Fc ; optional epilogue C = mask*(C - f)
__global__ __launch_bounds__(256) void k_gemm_right(
    const float* __restrict__ Bin,
    const float* __restrict__ Fre, const float* __restrict__ Fim,
    float* __restrict__ Cout, int conjF, int do_mask,
    const float* __restrict__ mask,
    const float* __restrict__ fdat) {
  __shared__ float Ar[TB][KC + 1], Ai[TB][KC + 1], Br2[KC][TB + 1], Bi2[KC][TB + 1];
  int b = blockIdx.z;
  int i0 = blockIdx.y * TB, j0 = blockIdx.x * TB;
  int tx = threadIdx.x % 16, ty = threadIdx.x / 16;
  float cr[4][4] = {}, ci[4][4] = {};
  const float* Bb = Bin + (size_t)b * HH * WW * 2;
  float fsign = conjF ? -1.f : 1.f;
  for (int k0 = 0; k0 < WW; k0 += KC) {
    __syncthreads();
    for (int t = threadIdx.x; t < TB * KC; t += 256) {
      int ii = t / KC, kk = t % KC;
      int ga = ((i0 + ii) * WW + k0 + kk) * 2;
      Ar[ii][kk] = Bb[ga];
      Ai[ii][kk] = Bb[ga + 1];
      int kk2 = t / TB, jj = t % TB;
      int gb = (k0 + kk2) * WW + j0 + jj;
      Br2[kk2][jj] = Fre[gb];
      Bi2[kk2][jj] = fsign * Fim[gb];
    }
    __syncthreads();
    for (int kk = 0; kk < KC; kk++) {
      float arr[4], ari[4], brr[4], bri[4];
      for (int d = 0; d < 4; d++) {
        arr[d] = Ar[ty + 16 * d][kk]; ari[d] = Ai[ty + 16 * d][kk];
        brr[d] = Br2[kk][tx + 16 * d]; bri[d] = Bi2[kk][tx + 16 * d];
      }
      for (int di = 0; di < 4; di++)
        for (int dj = 0; dj < 4; dj++) {
          cr[di][dj] += arr[di] * brr[dj] - ari[di] * bri[dj];
          ci[di][dj] += arr[di] * bri[dj] + ari[di] * brr[dj];
        }
    }
  }
  int n = b / CC;
  for (int di = 0; di < 4; di++)
    for (int dj = 0; dj < 4; dj++) {
      int i = i0 + ty + 16 * di, j = j0 + tx + 16 * dj;
      int oi = (b * HH * WW + i * WW + j) * 2;
      float vr = cr[di][dj], vi = ci[di][dj];
      if (do_mask) {
        float m = mask[n * HH * WW + i * WW + j];
        float fr = fdat[oi], fi = fdat[oi + 1];
        vr = m * (vr - fr);
        vi = m * (vi - fi);
      }
      Cout[oi]     = vr;
      Cout[oi + 1] = vi;
    }
}

// ---------------- K8: coil-combine with conj(sens) -------------------------
__global__ void k_coilsum(const float* __restrict__ Z,
                          const float* __restrict__ cs,
                          float* __restrict__ At) {
  int idx = blockIdx.x * blockDim.x + threadIdx.x;
  if (idx >= NN * HH * WW) return;
  int n = idx / (HH * WW), hw = idx % (HH * WW);
  float ar = 0.f, ai = 0.f;
  for (int c = 0; c < CC; c++) {
    int zi = ((n * CC + c) * HH * WW + hw) * 2;
    float zr = Z[zi], zim = Z[zi + 1];
    float crr = cs[zi], cii = cs[zi + 1];
    ar += zr * crr + zim * cii;
    ai += zim * crr - zr * cii;
  }
  At[idx * 2]     = ar;
  At[idx * 2 + 1] = ai;
}

// ---------------- K9: out = u - Ru - lamb*At -------------------------------
__global__ void k_final(const float* __restrict__ u_t,
                        const float* __restrict__ Ru,
                        const float* __restrict__ At,
                        const float* __restrict__ lamb,
                        float* __restrict__ out) {
  int idx = blockIdx.x * blockDim.x + threadIdx.x;
  if (idx >= NN * HH * WW * 2) return;
  float l = lamb[0];
  float v = u_t[idx] - Ru[idx] - l * At[idx];
  out[idx] = v;
}

extern "C" void kernel_launch(void* const* d_in, const int* in_sizes, int n_in,
                              void* d_out, int out_size, void* d_ws, size_t ws_size,
                              hipStream_t stream) {
  const float* u_t   = (const float*)d_in[0];
  const float* fdat  = (const float*)d_in[1];
  const float* cs    = (const float*)d_in[2];
  const float* mask  = (const float*)d_in[3];
  const float* ck    = (const float*)d_in[4];
  const float* w     = (const float*)d_in[5];
  const float* mu    = (const float*)d_in[6];
  const float* sigma = (const float*)d_in[7];
  const float* lamb  = (const float*)d_in[8];
  float* out = (float*)d_out;

  float* ws = (float*)d_ws;
  float* Fre  = ws;                       // 102400
  float* Fim  = Fre + 102400;             // 102400
  float* Ru   = Fim + 102400;             // 819200
  float* At   = Ru + 819200;              // 819200
  float* bufA = At + 819200;              // 12288000
  float* bufB = bufA + 12288000;          // 12288000
  float* fuk  = bufA;                     // alias (regularizer phase only; spills into bufB, fine)

  dim3 b16(16, 16);

  k_dft<<<(HH * WW + 255) / 256, 256, 0, stream>>>(Fre, Fim);
  k_conv_rbf<<<dim3(22, 22, NN * FF), b16, 0, stream>>>(u_t, ck, w, mu, sigma, fuk);
  k_convT<<<dim3(20, 20, NN), b16, 0, stream>>>(fuk, ck, Ru);
  k_umul<<<(NN * CC * HH * WW + 255) / 256, 256, 0, stream>>>(u_t, cs, bufA);
  k_gemm_left<<<dim3(5, 5, NCB), 256, 0, stream>>>(Fre, Fim, bufA, bufB, 0);
  k_gemm_right<<<dim3(5, 5, NCB), 256, 0, stream>>>(bufB, Fre, Fim, bufA, 0, 1, mask, fdat);
  k_gemm_left<<<dim3(5, 5, NCB), 256, 0, stream>>>(Fre, Fim, bufA, bufB, 1);
  k_gemm_right<<<dim3(5, 5, NCB), 256, 0, stream>>>(bufB, Fre, Fim, bufA, 1, 0, nullptr, nullptr);
  k_coilsum<<<(NN * HH * WW + 255) / 256, 256, 0, stream>>>(bufA, cs, At);
  k_final<<<(NN * HH * WW * 2 + 255) / 256, 256, 0, stream>>>(u_t, Ru, At, lamb, out);
}

// Round 3
// 831.694 us; speedup vs baseline: 3.4620x; 3.4620x over previous
//
#include <hip/hip_runtime.h>
#include <hip/hip_bf16.h>
#include <math.h>

#define NN 4
#define CC 15
#define HH 320
#define WW 320
#define HW (HH*WW)          // 102400
#define FF 32
#define KS 11
#define PADN 11
#define CPAD 5
#define HP 342
#define NK 31
#define NCB (NN*CC)

typedef short bf16x8 __attribute__((ext_vector_type(8)));
typedef float f32x4 __attribute__((ext_vector_type(4)));

__device__ __forceinline__ unsigned int pack_bf(float r, float i) {
  __hip_bfloat16 hr = __float2bfloat16(r), hi = __float2bfloat16(i);
  unsigned short ur = *(unsigned short*)&hr, ui = *(unsigned short*)&hi;
  return (unsigned int)ur | ((unsigned int)ui << 16);
}
__device__ __forceinline__ unsigned short f2b(float x) {
  __hip_bfloat16 h = __float2bfloat16(x);
  return *(unsigned short*)&h;
}
__device__ __forceinline__ float b2f(unsigned short u) {
  __hip_bfloat16 h = *(__hip_bfloat16*)&u;
  return __bfloat162float(h);
}

// ---------------- K0: centered orthonormal DFT matrix, bf16 pairs ----------
__global__ void k_dft(unsigned int* __restrict__ Fbf) {
  int idx = blockIdx.x * blockDim.x + threadIdx.x;
  if (idx >= HW) return;
  int k = idx / WW, n = idx % WW;
  int prod = (k - 160) * (n - 160);
  int r = prod % 320; if (r < 0) r += 320;
  float ang = -6.283185307179586f * (float)r / 320.0f;
  const float s = 0.05590169943749474f; // 1/sqrt(320)
  Fbf[idx] = pack_bf(cosf(ang) * s, sinf(ang) * s);
}

// ---------------- K1: reflect-pad u into channel planes --------------------
__global__ void k_pad(const float* __restrict__ u_t, float* __restrict__ upad) {
  int idx = blockIdx.x * blockDim.x + threadIdx.x;
  if (idx >= NN * 2 * HP * HP) return;
  int x = idx % HP, rem = idx / HP;
  int y = rem % HP; rem /= HP;
  int ch = rem % 2; int n = rem / 2;
  int py = y - PADN; py = py < 0 ? -py : (py >= HH ? 2 * (HH - 1) - py : py);
  int px = x - PADN; px = px < 0 ? -px : (px >= WW ? 2 * (WW - 1) - px : px);
  upad[idx] = u_t[((n * HH + py) * WW + px) * 2 + ch];
}

// ---------------- K2: conv(11x11, zero-pad 5) + RBF, all 32 feats/block ----
__global__ __launch_bounds__(256) void k_conv_rbf(
    const float* __restrict__ upad, const float* __restrict__ ck,
    const float* __restrict__ w, const float* __restrict__ mu,
    const float* __restrict__ sigma, unsigned short* __restrict__ fukb) {
  __shared__ float tIn[2 * 42 * 45];          // [ch][42 rows][45 stride]
  __shared__ float kker[FF * KS * KS * 2];    // same flat layout as ck
  __shared__ float wsh[FF * NK];
  __shared__ float mush[NK];
  int n = blockIdx.z;
  int y0 = blockIdx.y * 32, x0 = blockIdx.x * 32;
  int tid = threadIdx.x;
  for (int i = tid; i < FF * KS * KS * 2; i += 256) kker[i] = ck[i];
  for (int i = tid; i < FF * NK; i += 256) wsh[i] = w[i];
  if (tid < NK) mush[tid] = mu[tid];
  for (int i = tid; i < 2 * 42 * 42; i += 256) {
    int ch = i / (42 * 42); int r2 = i % (42 * 42);
    int yy = r2 / 42, xx = r2 % 42;
    int gy = y0 - 5 + yy, gx = x0 - 5 + xx;
    float v = 0.f;
    if (gy >= 0 && gy < HP && gx >= 0 && gx < HP)
      v = upad[((n * 2 + ch) * HP + gy) * HP + gx];
    tIn[(ch * 42 + yy) * 45 + xx] = v;
  }
  __syncthreads();
  int px = tid % 8, py = tid / 8;             // py 0..31, 4 px each in x
  int ybase = y0 + py, xbase = x0 + px * 4;
  float sg = sigma[0];
  float inv2s2 = 1.0f / (2.0f * sg * sg);
  for (int o = 0; o < FF; o++) {
    float acc[4] = {0.f, 0.f, 0.f, 0.f};
    for (int ky = 0; ky < KS; ky++) {
      const float* r0 = &tIn[((0) * 42 + py + ky) * 45 + px * 4];
      const float* r1 = &tIn[((1) * 42 + py + ky) * 45 + px * 4];
      float a[14], b[14];
      #pragma unroll
      for (int q = 0; q < 14; q++) { a[q] = r0[q]; b[q] = r1[q]; }
      #pragma unroll
      for (int kx = 0; kx < KS; kx++) {
        float k0 = kker[(o * 121 + ky * 11 + kx) * 2 + 0];
        float k1 = kker[(o * 121 + ky * 11 + kx) * 2 + 1];
        #pragma unroll
        for (int d = 0; d < 4; d++) acc[d] += a[kx + d] * k0 + b[kx + d] * k1;
      }
    }
    #pragma unroll
    for (int d = 0; d < 4; d++) {
      int y = ybase, x = xbase + d;
      if (y < HP && x < HP) {
        float v = acc[d], r = 0.f;
        for (int i = 0; i < NK; i++) {
          float dd = v - mush[i];
          r += wsh[o * NK + i] * __expf(-dd * dd * inv2s2);
        }
        fukb[((n * FF + o) * HP + y) * HP + x] = f2b(r);
      }
    }
  }
}

// ---------------- K3: transposed conv (adjoint), crop, /FF -----------------
__global__ __launch_bounds__(256) void k_convT(
    const unsigned short* __restrict__ fukb, const float* __restrict__ ck,
    float* __restrict__ Ru) {
  __shared__ float kw[FF * KS * KS * 2];
  __shared__ float tile[42 * 45];
  int n = blockIdx.z;
  int y0 = blockIdx.y * 32, x0 = blockIdx.x * 32;
  int tid = threadIdx.x;
  for (int i = tid; i < FF * KS * KS * 2; i += 256) kw[i] = ck[i];
  int px = tid % 8, py = tid / 8;
  float ar[4] = {0, 0, 0, 0}, ai[4] = {0, 0, 0, 0};
  for (int o = 0; o < FF; o++) {
    __syncthreads();
    for (int i = tid; i < 42 * 42; i += 256) {
      int yy = i / 42, xx = i % 42;
      tile[yy * 45 + xx] = b2f(fukb[((n * FF + o) * HP + y0 + 6 + yy) * HP + (x0 + 6 + xx)]);
    }
    __syncthreads();
    for (int ky = 0; ky < KS; ky++) {
      const float* rp = &tile[(py + 10 - ky) * 45 + px * 4];
      float a[14];
      #pragma unroll
      for (int q = 0; q < 14; q++) a[q] = rp[q];
      #pragma unroll
      for (int kx = 0; kx < KS; kx++) {
        float k0 = kw[(o * 121 + ky * 11 + kx) * 2 + 0];
        float k1 = kw[(o * 121 + ky * 11 + kx) * 2 + 1];
        #pragma unroll
        for (int d = 0; d < 4; d++) {
          float v = a[10 - kx + d];
          ar[d] += v * k0;
          ai[d] += v * k1;
        }
      }
    }
  }
  int y = y0 + py, x = x0 + px * 4;
  #pragma unroll
  for (int d = 0; d < 4; d++) {
    int oi = ((n * HH + y) * WW + x + d) * 2;
    Ru[oi]     = ar[d] / (float)FF;
    Ru[oi + 1] = ai[d] / (float)FF;
  }
}

// ---------------- K4: X0 = u * coil_sens (complex), bf16 pairs -------------
__global__ void k_umul(const float* __restrict__ u_t, const float* __restrict__ cs,
                       unsigned int* __restrict__ X0) {
  int idx = blockIdx.x * blockDim.x + threadIdx.x;
  if (idx >= NCB * HW) return;
  int hw = idx % HW;
  int n = (idx / HW) / CC;
  float ur = u_t[(n * HW + hw) * 2], ui = u_t[(n * HW + hw) * 2 + 1];
  float cr = cs[idx * 2], ci = cs[idx * 2 + 1];
  X0[idx] = pack_bf(ur * cr - ui * ci, ur * ci + ui * cr);
}

// ---------------- K5: batched complex GEMM via bf16 MFMA -------------------
// C = A * B (complex 320x320). A,B sources are bf16 complex-interleaved pairs.
// LDS holds A' = [Ar, -Ai_e] and A'' = [Ai_e, Ar] row-major (K-interleaved),
// B = [Br; Bi_e] transposed. Cr = A'.B, Ci = A''.B over K=640.
__global__ __launch_bounds__(256) void k_gemm(
    const unsigned int* __restrict__ Abase, long aStride,
    unsigned int xorA1, unsigned int xorA2,
    const unsigned int* __restrict__ Bbase, long bStride, unsigned int xorB,
    unsigned int* __restrict__ OutB, float* __restrict__ OutF, int mode,
    const float* __restrict__ mask, const float* __restrict__ fdat) {
  __shared__ unsigned int lA1[64 * 20], lA2[64 * 20], lB[64 * 20];
  int b = blockIdx.z;
  int i0 = blockIdx.y * 64, j0 = blockIdx.x * 64;
  const unsigned int* A = Abase + (size_t)b * aStride;
  const unsigned int* B = Bbase + (size_t)b * bStride;
  int tid = threadIdx.x;
  int lane = tid & 63, wave = tid >> 6;
  int wy = (wave >> 1) * 32, wx = (wave & 1) * 32;
  int m16 = lane & 15, kq = lane >> 4;
  f32x4 accR[2][2] = {}, accI[2][2] = {};
  int ar = tid >> 4, akc = tid & 15;
  int bj = tid & 63, bk0 = tid >> 6;
  const short* lA1s = (const short*)lA1;
  const short* lA2s = (const short*)lA2;
  const short* lBs  = (const short*)lB;
  for (int kc0 = 0; kc0 < WW; kc0 += 16) {
    __syncthreads();
    #pragma unroll
    for (int it = 0; it < 4; it++) {
      int r = ar + 16 * it;
      unsigned int p = A[(i0 + r) * WW + kc0 + akc];
      lA1[r * 20 + akc] = p ^ xorA1;
      lA2[r * 20 + akc] = ((p >> 16) | (p << 16)) ^ xorA2;
    }
    #pragma unroll
    for (int it = 0; it < 4; it++) {
      int kc = bk0 + 4 * it;
      unsigned int p = B[(kc0 + kc) * WW + j0 + bj];
      lB[bj * 20 + kc] = p ^ xorB;
    }
    __syncthreads();
    bf16x8 a1[2], a2[2], bb[2];
    #pragma unroll
    for (int d = 0; d < 2; d++) {
      int row = wy + d * 16 + m16;
      a1[d] = *(const bf16x8*)&lA1s[row * 40 + kq * 8];
      a2[d] = *(const bf16x8*)&lA2s[row * 40 + kq * 8];
      int col = wx + d * 16 + m16;
      bb[d] = *(const bf16x8*)&lBs[col * 40 + kq * 8];
    }
    #pragma unroll
    for (int di = 0; di < 2; di++)
      #pragma unroll
      for (int dj = 0; dj < 2; dj++) {
        accR[di][dj] = __builtin_amdgcn_mfma_f32_16x16x32_bf16(a1[di], bb[dj], accR[di][dj], 0, 0, 0);
        accI[di][dj] = __builtin_amdgcn_mfma_f32_16x16x32_bf16(a2[di], bb[dj], accI[di][dj], 0, 0, 0);
      }
  }
  int n = b / CC;
  #pragma unroll
  for (int di = 0; di < 2; di++)
    #pragma unroll
    for (int dj = 0; dj < 2; dj++)
      #pragma unroll
      for (int r = 0; r < 4; r++) {
        int row = i0 + wy + di * 16 + kq * 4 + r;
        int col = j0 + wx + dj * 16 + m16;
        float vr = accR[di][dj][r], vi = accI[di][dj][r];
        size_t idx = (size_t)b * HW + row * WW + col;
        if (mode == 1) {
          float m = mask[n * HW + row * WW + col];
          vr = m * (vr - fdat[idx * 2]);
          vi = m * (vi - fdat[idx * 2 + 1]);
        }
        if (mode == 2) {
          OutF[idx * 2] = vr; OutF[idx * 2 + 1] = vi;
        } else {
          OutB[idx] = pack_bf(vr, vi);
        }
      }
}

// ---------------- K6: coil-combine with conj(sens) -------------------------
__global__ void k_coilsum(const float* __restrict__ Z, const float* __restrict__ cs,
                          float* __restrict__ At) {
  int idx = blockIdx.x * blockDim.x + threadIdx.x;
  if (idx >= NN * HW) return;
  int n = idx / HW, hw = idx % HW;
  float ar = 0.f, ai = 0.f;
  for (int c = 0; c < CC; c++) {
    int zi = ((n * CC + c) * HW + hw) * 2;
    float zr = Z[zi], zim = Z[zi + 1];
    float crr = cs[zi], cii = cs[zi + 1];
    ar += zr * crr + zim * cii;
    ai += zim * crr - zr * cii;
  }
  At[idx * 2] = ar;
  At[idx * 2 + 1] = ai;
}

// ---------------- K7: out = u - Ru - lamb*At -------------------------------
__global__ void k_final(const float* __restrict__ u_t, const float* __restrict__ Ru,
                        const float* __restrict__ At, const float* __restrict__ lamb,
                        float* __restrict__ out) {
  int idx = blockIdx.x * blockDim.x + threadIdx.x;
  if (idx >= NN * HW * 2) return;
  out[idx] = u_t[idx] - Ru[idx] - lamb[0] * At[idx];
}

extern "C" void kernel_launch(void* const* d_in, const int* in_sizes, int n_in,
                              void* d_out, int out_size, void* d_ws, size_t ws_size,
                              hipStream_t stream) {
  const float* u_t   = (const float*)d_in[0];
  const float* fdat  = (const float*)d_in[1];
  const float* cs    = (const float*)d_in[2];
  const float* mask  = (const float*)d_in[3];
  const float* ck    = (const float*)d_in[4];
  const float* w     = (const float*)d_in[5];
  const float* mu    = (const float*)d_in[6];
  const float* sigma = (const float*)d_in[7];
  const float* lamb  = (const float*)d_in[8];
  float* out = (float*)d_out;

  // ws layout (4-byte words):
  //  Fbf  @0        102400   (bf16 pair u32)
  //  Ru   @102400   819200   f32
  //  At   @921600   819200   f32
  //  big  @1740800:
  //    phase R : upad f32 [935712] ; fukb bf16 [14971392 shorts = 7485696 w]
  //    phase DC: P u32[6144000] ; Q u32[6144000] ; Y4 f32[12288000]
  unsigned int* wsw = (unsigned int*)d_ws;
  unsigned int* Fbf = wsw;
  float* Ru = (float*)(wsw + 102400);
  float* At = (float*)(wsw + 921600);
  unsigned int* big = wsw + 1740800;
  float* upad = (float*)big;
  unsigned short* fukb = (unsigned short*)(big + 935712);
  unsigned int* P = big;
  unsigned int* Q = big + 6144000;
  float* Y4 = (float*)(big + 12288000);

  k_dft<<<(HW + 255) / 256, 256, 0, stream>>>(Fbf);
  k_pad<<<(NN * 2 * HP * HP + 255) / 256, 256, 0, stream>>>(u_t, upad);
  k_conv_rbf<<<dim3(11, 11, NN), 256, 0, stream>>>(upad, ck, w, mu, sigma, fukb);
  k_convT<<<dim3(10, 10, NN), 256, 0, stream>>>(fukb, ck, Ru);
  k_umul<<<(NCB * HW + 255) / 256, 256, 0, stream>>>(u_t, cs, P);
  // pass1: Y1 = F . X0           (left: A=F)
  k_gemm<<<dim3(5, 5, NCB), 256, 0, stream>>>(Fbf, 0L, 0x80000000u, 0u,
                                              P, (long)HW, 0u,
                                              Q, nullptr, 0, nullptr, nullptr);
  // pass2: Y2 = mask*(Y1 . F - f) (right: B=F)
  k_gemm<<<dim3(5, 5, NCB), 256, 0, stream>>>(Q, (long)HW, 0x80000000u, 0u,
                                              Fbf, 0L, 0u,
                                              P, nullptr, 1, mask, fdat);
  // pass3: Y3 = conj(F) . Y2     (left, conj A)
  k_gemm<<<dim3(5, 5, NCB), 256, 0, stream>>>(Fbf, 0L, 0u, 0x00008000u,
                                              P, (long)HW, 0u,
                                              Q, nullptr, 0, nullptr, nullptr);
  // pass4: Y4 = Y3 . conj(F)     (right, conj B), f32 out
  k_gemm<<<dim3(5, 5, NCB), 256, 0, stream>>>(Q, (long)HW, 0x80000000u, 0u,
                                              Fbf, 0L, 0x80000000u,
                                              nullptr, Y4, 2, nullptr, nullptr);
  k_coilsum<<<(NN * HW + 255) / 256, 256, 0, stream>>>(Y4, cs, At);
  k_final<<<(NN * HW * 2 + 255) / 256, 256, 0, stream>>>(u_t, Ru, At, lamb, out);
}

// Round 4
// 571.361 us; speedup vs baseline: 5.0394x; 1.4556x over previous
//
#include <hip/hip_runtime.h>
#include <hip/hip_bf16.h>
#include <math.h>

#define NN 4
#define CC 15
#define HH 320
#define WW 320
#define HW (HH*WW)          // 102400
#define FF 32
#define KS 11
#define PADN 11
#define CPAD 5
#define HP 342
#define NK 31
#define NCB (NN*CC)

typedef short bf16x8 __attribute__((ext_vector_type(8)));
typedef float f32x4 __attribute__((ext_vector_type(4)));

__device__ __forceinline__ unsigned int pack_bf(float r, float i) {
  __hip_bfloat16 hr = __float2bfloat16(r), hi = __float2bfloat16(i);
  unsigned short ur = *(unsigned short*)&hr, ui = *(unsigned short*)&hi;
  return (unsigned int)ur | ((unsigned int)ui << 16);
}
__device__ __forceinline__ unsigned short f2b(float x) {
  __hip_bfloat16 h = __float2bfloat16(x);
  return *(unsigned short*)&h;
}
__device__ __forceinline__ float b2f(unsigned short u) {
  __hip_bfloat16 h = *(__hip_bfloat16*)&u;
  return __bfloat162float(h);
}

// ---------------- K0: centered orthonormal DFT matrix, bf16 pairs ----------
__global__ void k_dft(unsigned int* __restrict__ Fbf) {
  int idx = blockIdx.x * blockDim.x + threadIdx.x;
  if (idx >= HW) return;
  int k = idx / WW, n = idx % WW;
  int prod = (k - 160) * (n - 160);
  int r = prod % 320; if (r < 0) r += 320;
  float ang = -6.283185307179586f * (float)r / 320.0f;
  const float s = 0.05590169943749474f; // 1/sqrt(320)
  Fbf[idx] = pack_bf(cosf(ang) * s, sinf(ang) * s);
}

// ---------------- K1: reflect-pad u into channel planes --------------------
__global__ void k_pad(const float* __restrict__ u_t, float* __restrict__ upad) {
  int idx = blockIdx.x * blockDim.x + threadIdx.x;
  if (idx >= NN * 2 * HP * HP) return;
  int x = idx % HP, rem = idx / HP;
  int y = rem % HP; rem /= HP;
  int ch = rem % 2; int n = rem / 2;
  int py = y - PADN; py = py < 0 ? -py : (py >= HH ? 2 * (HH - 1) - py : py);
  int px = x - PADN; px = px < 0 ? -px : (px >= WW ? 2 * (WW - 1) - px : px);
  upad[idx] = u_t[((n * HH + py) * WW + px) * 2 + ch];
}

// ---------------- K2: conv(11x11) + RBF, 8 features/block ------------------
// weights via wave-uniform global reads (SGPR); input tile in LDS, float4 reads
__global__ __launch_bounds__(256) void k_conv_rbf(
    const float* __restrict__ upad, const float* __restrict__ ck,
    const float* __restrict__ w, const float* __restrict__ mu,
    const float* __restrict__ sigma, unsigned short* __restrict__ fukb) {
  __shared__ float tIn[2 * 42 * 44];   // stride 44, float4-aligned
  __shared__ float wshL[8 * NK];
  int zz = blockIdx.z;
  int n = zz >> 2, og = zz & 3;
  int oBase = og * 8;
  int y0 = blockIdx.y * 32, x0 = blockIdx.x * 32;
  int tid = threadIdx.x;
  for (int i = tid; i < 8 * NK; i += 256)
    wshL[i] = w[(oBase + i / NK) * NK + (i % NK)];
  for (int i = tid; i < 2 * 42 * 42; i += 256) {
    int ch = i / (42 * 42); int r2 = i % (42 * 42);
    int yy = r2 / 42, xx = r2 % 42;
    int gy = y0 - 5 + yy, gx = x0 - 5 + xx;
    float v = 0.f;
    if (gy >= 0 && gy < HP && gx >= 0 && gx < HP)
      v = upad[((n * 2 + ch) * HP + gy) * HP + gx];
    tIn[(ch * 42 + yy) * 44 + xx] = v;
  }
  __syncthreads();
  int px = tid & 7, py = tid >> 3;
  float acc[8][4] = {};
  for (int ky = 0; ky < KS; ky++) {
    float A[16], Bv[16];
    const f32x4* pa = (const f32x4*)&tIn[(0 * 42 + py + ky) * 44 + px * 4];
    const f32x4* pb = (const f32x4*)&tIn[(1 * 42 + py + ky) * 44 + px * 4];
    #pragma unroll
    for (int q = 0; q < 4; q++) {
      f32x4 va = pa[q], vb = pb[q];
      #pragma unroll
      for (int e = 0; e < 4; e++) { A[q * 4 + e] = va[e]; Bv[q * 4 + e] = vb[e]; }
    }
    #pragma unroll
    for (int o = 0; o < 8; o++) {
      const float* kg = &ck[((oBase + o) * 121 + ky * 11) * 2];
      #pragma unroll
      for (int kx = 0; kx < KS; kx++) {
        float k0 = kg[kx * 2], k1 = kg[kx * 2 + 1];
        #pragma unroll
        for (int d = 0; d < 4; d++)
          acc[o][d] += A[kx + d] * k0 + Bv[kx + d] * k1;
      }
    }
  }
  float mu0 = mu[0];
  float dmu = mu[1] - mu[0];
  float invD = 1.0f / dmu;
  float sg = sigma[0];
  float nInv = -1.0f / (2.0f * sg * sg);
  int ybase = y0 + py;
  #pragma unroll
  for (int o = 0; o < 8; o++) {
    #pragma unroll
    for (int d = 0; d < 4; d++) {
      int y = ybase, x = x0 + px * 4 + d;
      if (y < HP && x < HP) {
        float v = acc[o][d];
        float f0 = fminf(fmaxf(rintf((v - mu0) * invD) - 5.0f, 0.0f), 20.0f);
        int i0 = (int)f0;
        float muW = mu0 + f0 * dmu;
        float r = 0.f;
        #pragma unroll
        for (int ii = 0; ii < 11; ii++) {
          float dd = v - (muW + (float)ii * dmu);
          r += wshL[o * NK + i0 + ii] * __expf(dd * dd * nInv);
        }
        fukb[((n * FF + oBase + o) * HP + y) * HP + x] = f2b(r);
      }
    }
  }
}

// ---------------- K3: transposed conv partials, 8 features/block -----------
__global__ __launch_bounds__(256) void k_convT(
    const unsigned short* __restrict__ fukb, const float* __restrict__ ck,
    float* __restrict__ RuP) {
  __shared__ float tile[42 * 44];
  int zz = blockIdx.z; int n = zz >> 2, og = zz & 3; int oBase = og * 8;
  int y0 = blockIdx.y * 32, x0 = blockIdx.x * 32;
  int tid = threadIdx.x; int px = tid & 7, py = tid >> 3;
  float ar[4] = {}, ai[4] = {};
  for (int oL = 0; oL < 8; oL++) {
    int o = oBase + oL;
    __syncthreads();
    for (int i = tid; i < 42 * 42; i += 256) {
      int yy = i / 42, xx = i % 42;
      tile[yy * 44 + xx] = b2f(fukb[((n * FF + o) * HP + y0 + 6 + yy) * HP + x0 + 6 + xx]);
    }
    __syncthreads();
    #pragma unroll
    for (int ky = 0; ky < KS; ky++) {
      float A[16];
      const f32x4* pa = (const f32x4*)&tile[(py + 10 - ky) * 44 + px * 4];
      #pragma unroll
      for (int q = 0; q < 4; q++) {
        f32x4 va = pa[q];
        #pragma unroll
        for (int e = 0; e < 4; e++) A[q * 4 + e] = va[e];
      }
      const float* kg = &ck[(o * 121 + ky * 11) * 2];
      #pragma unroll
      for (int kx = 0; kx < KS; kx++) {
        float k0 = kg[kx * 2], k1 = kg[kx * 2 + 1];
        #pragma unroll
        for (int d = 0; d < 4; d++) {
          float v = A[10 - kx + d];
          ar[d] += v * k0;
          ai[d] += v * k1;
        }
      }
    }
  }
  int y = y0 + py, x = x0 + px * 4;
  #pragma unroll
  for (int d = 0; d < 4; d++) {
    size_t oi = ((size_t)(og * NN + n) * HH * WW + (size_t)y * WW + x + d) * 2;
    RuP[oi]     = ar[d];
    RuP[oi + 1] = ai[d];
  }
}

// ---------------- K4: X0 = u * coil_sens (complex), bf16 pairs -------------
__global__ void k_umul(const float* __restrict__ u_t, const float* __restrict__ cs,
                       unsigned int* __restrict__ X0) {
  int idx = blockIdx.x * blockDim.x + threadIdx.x;
  if (idx >= NCB * HW) return;
  int hw = idx % HW;
  int n = (idx / HW) / CC;
  float ur = u_t[(n * HW + hw) * 2], ui = u_t[(n * HW + hw) * 2 + 1];
  float cr = cs[idx * 2], ci = cs[idx * 2 + 1];
  X0[idx] = pack_bf(ur * cr - ui * ci, ur * ci + ui * cr);
}

// ---------------- K5: batched complex GEMM via bf16 MFMA -------------------
__global__ __launch_bounds__(256) void k_gemm(
    const unsigned int* __restrict__ Abase, long aStride,
    unsigned int xorA1, unsigned int xorA2,
    const unsigned int* __restrict__ Bbase, long bStride, unsigned int xorB,
    unsigned int* __restrict__ OutB, int mode,
    const float* __restrict__ mask, const float* __restrict__ fdat) {
  __shared__ unsigned int lA1[64 * 20], lA2[64 * 20], lB[64 * 20];
  int b = blockIdx.z;
  int i0 = blockIdx.y * 64, j0 = blockIdx.x * 64;
  const unsigned int* A = Abase + (size_t)b * aStride;
  const unsigned int* B = Bbase + (size_t)b * bStride;
  int tid = threadIdx.x;
  int lane = tid & 63, wave = tid >> 6;
  int wy = (wave >> 1) * 32, wx = (wave & 1) * 32;
  int m16 = lane & 15, kq = lane >> 4;
  f32x4 accR[2][2] = {}, accI[2][2] = {};
  int ar = tid >> 4, akc = tid & 15;
  int bj = tid & 63, bk0 = tid >> 6;
  const short* lA1s = (const short*)lA1;
  const short* lA2s = (const short*)lA2;
  const short* lBs  = (const short*)lB;
  for (int kc0 = 0; kc0 < WW; kc0 += 16) {
    __syncthreads();
    #pragma unroll
    for (int it = 0; it < 4; it++) {
      int r = ar + 16 * it;
      unsigned int p = A[(i0 + r) * WW + kc0 + akc];
      lA1[r * 20 + akc] = p ^ xorA1;
      lA2[r * 20 + akc] = ((p >> 16) | (p << 16)) ^ xorA2;
    }
    #pragma unroll
    for (int it = 0; it < 4; it++) {
      int kc = bk0 + 4 * it;
      unsigned int p = B[(kc0 + kc) * WW + j0 + bj];
      lB[bj * 20 + kc] = p ^ xorB;
    }
    __syncthreads();
    bf16x8 a1[2], a2[2], bb[2];
    #pragma unroll
    for (int d = 0; d < 2; d++) {
      int row = wy + d * 16 + m16;
      a1[d] = *(const bf16x8*)&lA1s[row * 40 + kq * 8];
      a2[d] = *(const bf16x8*)&lA2s[row * 40 + kq * 8];
      int col = wx + d * 16 + m16;
      bb[d] = *(const bf16x8*)&lBs[col * 40 + kq * 8];
    }
    #pragma unroll
    for (int di = 0; di < 2; di++)
      #pragma unroll
      for (int dj = 0; dj < 2; dj++) {
        accR[di][dj] = __builtin_amdgcn_mfma_f32_16x16x32_bf16(a1[di], bb[dj], accR[di][dj], 0, 0, 0);
        accI[di][dj] = __builtin_amdgcn_mfma_f32_16x16x32_bf16(a2[di], bb[dj], accI[di][dj], 0, 0, 0);
      }
  }
  int n = b / CC;
  #pragma unroll
  for (int di = 0; di < 2; di++)
    #pragma unroll
    for (int dj = 0; dj < 2; dj++)
      #pragma unroll
      for (int r = 0; r < 4; r++) {
        int row = i0 + wy + di * 16 + kq * 4 + r;
        int col = j0 + wx + dj * 16 + m16;
        float vr = accR[di][dj][r], vi = accI[di][dj][r];
        size_t idx = (size_t)b * HW + row * WW + col;
        if (mode == 1) {
          float m = mask[n * HW + row * WW + col];
          vr = m * (vr - fdat[idx * 2]);
          vi = m * (vi - fdat[idx * 2 + 1]);
        }
        OutB[idx] = pack_bf(vr, vi);
      }
}

// ---------------- K6: coil-combine with conj(sens), bf16-pair input --------
__global__ void k_coilsum(const unsigned int* __restrict__ Z, const float* __restrict__ cs,
                          float* __restrict__ At) {
  int idx = blockIdx.x * blockDim.x + threadIdx.x;
  if (idx >= NN * HW) return;
  int n = idx / HW, hw = idx % HW;
  float ar = 0.f, ai = 0.f;
  for (int c = 0; c < CC; c++) {
    size_t zi = (size_t)(n * CC + c) * HW + hw;
    unsigned int p = Z[zi];
    float zr = b2f((unsigned short)(p & 0xffff));
    float zim = b2f((unsigned short)(p >> 16));
    float crr = cs[zi * 2], cii = cs[zi * 2 + 1];
    ar += zr * crr + zim * cii;
    ai += zim * crr - zr * cii;
  }
  At[idx * 2] = ar;
  At[idx * 2 + 1] = ai;
}

// ---------------- K7: out = u - sum(RuP)/FF - lamb*At ----------------------
__global__ void k_final(const float* __restrict__ u_t, const float* __restrict__ RuP,
                        const float* __restrict__ At, const float* __restrict__ lamb,
                        float* __restrict__ out) {
  int idx = blockIdx.x * blockDim.x + threadIdx.x;
  if (idx >= NN * HW * 2) return;
  float ru = RuP[idx] + RuP[idx + 819200] + RuP[idx + 2 * 819200] + RuP[idx + 3 * 819200];
  out[idx] = u_t[idx] - ru * (1.0f / (float)FF) - lamb[0] * At[idx];
}

extern "C" void kernel_launch(void* const* d_in, const int* in_sizes, int n_in,
                              void* d_out, int out_size, void* d_ws, size_t ws_size,
                              hipStream_t stream) {
  const float* u_t   = (const float*)d_in[0];
  const float* fdat  = (const float*)d_in[1];
  const float* cs    = (const float*)d_in[2];
  const float* mask  = (const float*)d_in[3];
  const float* ck    = (const float*)d_in[4];
  const float* w     = (const float*)d_in[5];
  const float* mu    = (const float*)d_in[6];
  const float* sigma = (const float*)d_in[7];
  const float* lamb  = (const float*)d_in[8];
  float* out = (float*)d_out;

  // ws layout (4-byte words), total 16486400 w = 66 MB:
  //  Fbf @0              102400
  //  At  @102400         819200
  //  RuP @921600         4*819200 = 3276800
  //  big @4198400        12288000  (P | Q; conv phase aliases upad+fukb here)
  unsigned int* wsw = (unsigned int*)d_ws;
  unsigned int* Fbf = wsw;
  float* At  = (float*)(wsw + 102400);
  float* RuP = (float*)(wsw + 921600);
  unsigned int* big = wsw + 4198400;
  float* upad = (float*)big;
  unsigned short* fukb = (unsigned short*)(big + 935712);
  unsigned int* P = big;
  unsigned int* Q = big + 6144000;

  k_dft<<<(HW + 255) / 256, 256, 0, stream>>>(Fbf);
  k_pad<<<(NN * 2 * HP * HP + 255) / 256, 256, 0, stream>>>(u_t, upad);
  k_conv_rbf<<<dim3(11, 11, NN * 4), 256, 0, stream>>>(upad, ck, w, mu, sigma, fukb);
  k_convT<<<dim3(10, 10, NN * 4), 256, 0, stream>>>(fukb, ck, RuP);
  k_umul<<<(NCB * HW + 255) / 256, 256, 0, stream>>>(u_t, cs, P);
  // pass1: Y1 = F . X0
  k_gemm<<<dim3(5, 5, NCB), 256, 0, stream>>>(Fbf, 0L, 0x80000000u, 0u,
                                              P, (long)HW, 0u,
                                              Q, 0, nullptr, nullptr);
  // pass2: Y2 = mask*(Y1 . F - f)
  k_gemm<<<dim3(5, 5, NCB), 256, 0, stream>>>(Q, (long)HW, 0x80000000u, 0u,
                                              Fbf, 0L, 0u,
                                              P, 1, mask, fdat);
  // pass3: Y3 = conj(F) . Y2
  k_gemm<<<dim3(5, 5, NCB), 256, 0, stream>>>(Fbf, 0L, 0u, 0x00008000u,
                                              P, (long)HW, 0u,
                                              Q, 0, nullptr, nullptr);
  // pass4: Y4 = Y3 . conj(F)
  k_gemm<<<dim3(5, 5, NCB), 256, 0, stream>>>(Q, (long)HW, 0x80000000u, 0u,
                                              Fbf, 0L, 0x80000000u,
                                              P, 0, nullptr, nullptr);
  k_coilsum<<<(NN * HW + 255) / 256, 256, 0, stream>>>(P, cs, At);
  k_final<<<(NN * HW * 2 + 255) / 256, 256, 0, stream>>>(u_t, RuP, At, lamb, out);
}

// Round 5
// 481.001 us; speedup vs baseline: 5.9860x; 1.1879x over previous
//
#include <hip/hip_runtime.h>
#include <hip/hip_bf16.h>
#include <math.h>

#define NN 4
#define CC 15
#define HH 320
#define WW 320
#define HW (HH*WW)          // 102400
#define FF 32
#define KS 11
#define PADN 11
#define CPAD 5
#define HP 342
#define NK 31
#define NCB (NN*CC)

typedef short bf16x8 __attribute__((ext_vector_type(8)));
typedef float f32x4 __attribute__((ext_vector_type(4)));

#define MFMA16 __builtin_amdgcn_mfma_f32_16x16x32_bf16

__device__ __forceinline__ unsigned int pack_bf(float r, float i) {
  __hip_bfloat16 hr = __float2bfloat16(r), hi = __float2bfloat16(i);
  unsigned short ur = *(unsigned short*)&hr, ui = *(unsigned short*)&hi;
  return (unsigned int)ur | ((unsigned int)ui << 16);
}
__device__ __forceinline__ unsigned short f2b(float x) {
  __hip_bfloat16 h = __float2bfloat16(x);
  return *(unsigned short*)&h;
}
__device__ __forceinline__ float b2f(unsigned short u) {
  __hip_bfloat16 h = *(__hip_bfloat16*)&u;
  return __bfloat162float(h);
}

// ---------------- K0: centered orthonormal DFT matrix, bf16 pairs ----------
__global__ void k_dft(unsigned int* __restrict__ Fbf) {
  int idx = blockIdx.x * blockDim.x + threadIdx.x;
  if (idx >= HW) return;
  int k = idx / WW, n = idx % WW;
  int prod = (k - 160) * (n - 160);
  int r = prod % 320; if (r < 0) r += 320;
  float ang = -6.283185307179586f * (float)r / 320.0f;
  const float s = 0.05590169943749474f; // 1/sqrt(320)
  Fbf[idx] = pack_bf(cosf(ang) * s, sinf(ang) * s);
}

// ---------------- K0b: prepack conv weights for MFMA A-operand -------------
// Wpk[o][kw] u32, kw=0..175: ky=kw/16, kx=kw%16; bf16 pair (ch0,ch1); kx>10 -> 0
__global__ void k_prep(const float* __restrict__ ck, unsigned int* __restrict__ Wpk) {
  int idx = blockIdx.x * blockDim.x + threadIdx.x;
  if (idx >= 32 * 176) return;
  int o = idx / 176, kw = idx % 176;
  int ky = kw / 16, kx = kw % 16;
  unsigned int v = 0;
  if (kx <= 10) {
    const float* p = &ck[(o * 121 + ky * 11 + kx) * 2];
    v = pack_bf(p[0], p[1]);
  }
  Wpk[idx] = v;
}

// ---------------- K2: conv(11x11) + RBF via MFMA implicit GEMM -------------
// block: 16y x 16x pixel tile, all 32 features. wave w handles y-rows w*4..w*4+3.
__global__ __launch_bounds__(256) void k_conv_rbf_mfma(
    const float* __restrict__ u_t, const unsigned int* __restrict__ Wpk,
    const float* __restrict__ w, const float* __restrict__ mu,
    const float* __restrict__ sigma, unsigned short* __restrict__ fukb) {
  __shared__ unsigned int lW[32 * 180];   // weights, row stride 180 dw
  __shared__ unsigned int tIn[26 * 32];   // input tile, (ch0,ch1) bf16 pairs
  __shared__ float wl[32 * 36];           // RBF weights, stride 36
  int n = blockIdx.z;
  int y0 = blockIdx.y * 16, x0 = blockIdx.x * 16;
  int tid = threadIdx.x;
  for (int i = tid; i < 32 * 176; i += 256)
    lW[(i / 176) * 180 + (i % 176)] = Wpk[i];
  for (int i = tid; i < 32 * 36; i += 256) {
    int idx = i % 36;
    wl[i] = (idx < 31) ? w[(i / 36) * 31 + idx] : 0.f;
  }
  for (int i = tid; i < 26 * 32; i += 256) {
    int rr = i >> 5, cc = i & 31;
    unsigned int v = 0;
    if (cc < 26) {
      int py = y0 + rr - 5, px = x0 + cc - 5;   // coords in zero-padded 342+ domain
      if (py >= 0 && py < HP && px >= 0 && px < HP) {
        int uy = py - PADN; uy = uy < 0 ? -uy : (uy >= HH ? 2 * (HH - 1) - uy : uy);
        int ux = px - PADN; ux = ux < 0 ? -ux : (ux >= WW ? 2 * (WW - 1) - ux : ux);
        const float* up = &u_t[((n * HH + uy) * WW + ux) * 2];
        v = pack_bf(up[0], up[1]);
      }
    }
    tIn[i] = v;
  }
  __syncthreads();
  int lane = tid & 63, wave = tid >> 6;
  int m16 = lane & 15, kq = lane >> 4;
  const short* lWs = (const short*)lW;
  f32x4 acc[4][2] = {};
  for (int ky = 0; ky < 11; ky++) {
    bf16x8 af0 = *(const bf16x8*)&lWs[m16 * 360 + ky * 32 + kq * 8];
    bf16x8 af1 = *(const bf16x8*)&lWs[(m16 + 16) * 360 + ky * 32 + kq * 8];
    #pragma unroll
    for (int nt = 0; nt < 4; nt++) {
      int rr = wave * 4 + nt + ky;
      int c0 = rr * 32 + m16 + kq * 4;
      union { unsigned int u[4]; bf16x8 v; } bu;
      bu.u[0] = tIn[c0]; bu.u[1] = tIn[c0 + 1];
      bu.u[2] = tIn[c0 + 2]; bu.u[3] = tIn[c0 + 3];
      acc[nt][0] = MFMA16(af0, bu.v, acc[nt][0], 0, 0, 0);
      acc[nt][1] = MFMA16(af1, bu.v, acc[nt][1], 0, 0, 0);
    }
  }
  // RBF epilogue + store. C layout: col=lane&15 (x), row=kq*4+r (feature)
  float mu0 = mu[0];
  float dmu = mu[1] - mu[0];
  float invD = 1.0f / dmu;
  float sg = sigma[0];
  float nInv = -1.0f / (2.0f * sg * sg);
  #pragma unroll
  for (int nt = 0; nt < 4; nt++) {
    int Y = y0 + wave * 4 + nt;
    int X = x0 + m16;
    if (Y >= HP || X >= HP) continue;
    #pragma unroll
    for (int mt = 0; mt < 2; mt++) {
      #pragma unroll
      for (int r = 0; r < 4; r++) {
        int o = mt * 16 + kq * 4 + r;
        float v = acc[nt][mt][r];
        float cf = fminf(fmaxf(rintf((v - mu0) * invD), 0.f), 30.f);
        int i0a = ((int)cf - 5) & ~3;
        if (i0a < 0) i0a = 0; if (i0a > 20) i0a = 20;
        const f32x4* wp = (const f32x4*)&wl[o * 36 + i0a];
        f32x4 w0 = wp[0], w1 = wp[1], w2 = wp[2];
        float base = mu0 + (float)i0a * dmu;
        float res = 0.f;
        #pragma unroll
        for (int ii = 0; ii < 12; ii++) {
          float d = v - (base + (float)ii * dmu);
          float wv = (ii < 4) ? w0[ii] : (ii < 8) ? w1[ii - 4] : w2[ii - 8];
          res += wv * __expf(d * d * nInv);
        }
        fukb[((size_t)(n * FF + o) * HP + Y) * HP + X] = f2b(res);
      }
    }
  }
}

// ---------------- K3: transposed conv partials, 8 features/block -----------
__global__ __launch_bounds__(256) void k_convT(
    const unsigned short* __restrict__ fukb, const float* __restrict__ ck,
    float* __restrict__ RuP) {
  __shared__ float tile[42 * 44];
  int zz = blockIdx.z; int n = zz >> 2, og = zz & 3; int oBase = og * 8;
  int y0 = blockIdx.y * 32, x0 = blockIdx.x * 32;
  int tid = threadIdx.x; int px = tid & 7, py = tid >> 3;
  float ar[4] = {}, ai[4] = {};
  for (int oL = 0; oL < 8; oL++) {
    int o = oBase + oL;
    __syncthreads();
    for (int i = tid; i < 42 * 42; i += 256) {
      int yy = i / 42, xx = i % 42;
      tile[yy * 44 + xx] = b2f(fukb[((size_t)(n * FF + o) * HP + y0 + 6 + yy) * HP + x0 + 6 + xx]);
    }
    __syncthreads();
    #pragma unroll
    for (int ky = 0; ky < KS; ky++) {
      float A[16];
      const f32x4* pa = (const f32x4*)&tile[(py + 10 - ky) * 44 + px * 4];
      #pragma unroll
      for (int q = 0; q < 4; q++) {
        f32x4 va = pa[q];
        #pragma unroll
        for (int e = 0; e < 4; e++) A[q * 4 + e] = va[e];
      }
      const float* kg = &ck[(o * 121 + ky * 11) * 2];
      #pragma unroll
      for (int kx = 0; kx < KS; kx++) {
        float k0 = kg[kx * 2], k1 = kg[kx * 2 + 1];
        #pragma unroll
        for (int d = 0; d < 4; d++) {
          float v = A[10 - kx + d];
          ar[d] += v * k0;
          ai[d] += v * k1;
        }
      }
    }
  }
  int y = y0 + py, x = x0 + px * 4;
  #pragma unroll
  for (int d = 0; d < 4; d++) {
    size_t oi = ((size_t)(og * NN + n) * HH * WW + (size_t)y * WW + x + d) * 2;
    RuP[oi]     = ar[d];
    RuP[oi + 1] = ai[d];
  }
}

// ---------------- K4: X0 = u * coil_sens (complex), bf16 pairs -------------
__global__ void k_umul(const float* __restrict__ u_t, const float* __restrict__ cs,
                       unsigned int* __restrict__ X0) {
  int idx = blockIdx.x * blockDim.x + threadIdx.x;
  if (idx >= NCB * HW) return;
  int hw = idx % HW;
  int n = (idx / HW) / CC;
  float ur = u_t[(n * HW + hw) * 2], ui = u_t[(n * HW + hw) * 2 + 1];
  float cr = cs[idx * 2], ci = cs[idx * 2 + 1];
  X0[idx] = pack_bf(ur * cr - ui * ci, ur * ci + ui * cr);
}

// ---------------- K5: batched complex GEMM via bf16 MFMA -------------------
__global__ __launch_bounds__(256) void k_gemm(
    const unsigned int* __restrict__ Abase, long aStride,
    unsigned int xorA1, unsigned int xorA2,
    const unsigned int* __restrict__ Bbase, long bStride, unsigned int xorB,
    unsigned int* __restrict__ OutB, int mode,
    const float* __restrict__ mask, const float* __restrict__ fdat) {
  __shared__ unsigned int lA1[64 * 20], lA2[64 * 20], lB[64 * 20];
  int b = blockIdx.z;
  int i0 = blockIdx.y * 64, j0 = blockIdx.x * 64;
  const unsigned int* A = Abase + (size_t)b * aStride;
  const unsigned int* B = Bbase + (size_t)b * bStride;
  int tid = threadIdx.x;
  int lane = tid & 63, wave = tid >> 6;
  int wy = (wave >> 1) * 32, wx = (wave & 1) * 32;
  int m16 = lane & 15, kq = lane >> 4;
  f32x4 accR[2][2] = {}, accI[2][2] = {};
  int ar = tid >> 4, akc = tid & 15;
  int bj = tid & 63, bk0 = tid >> 6;
  const short* lA1s = (const short*)lA1;
  const short* lA2s = (const short*)lA2;
  const short* lBs  = (const short*)lB;
  for (int kc0 = 0; kc0 < WW; kc0 += 16) {
    __syncthreads();
    #pragma unroll
    for (int it = 0; it < 4; it++) {
      int r = ar + 16 * it;
      unsigned int p = A[(i0 + r) * WW + kc0 + akc];
      lA1[r * 20 + akc] = p ^ xorA1;
      lA2[r * 20 + akc] = ((p >> 16) | (p << 16)) ^ xorA2;
    }
    #pragma unroll
    for (int it = 0; it < 4; it++) {
      int kc = bk0 + 4 * it;
      unsigned int p = B[(kc0 + kc) * WW + j0 + bj];
      lB[bj * 20 + kc] = p ^ xorB;
    }
    __syncthreads();
    bf16x8 a1[2], a2[2], bb[2];
    #pragma unroll
    for (int d = 0; d < 2; d++) {
      int row = wy + d * 16 + m16;
      a1[d] = *(const bf16x8*)&lA1s[row * 40 + kq * 8];
      a2[d] = *(const bf16x8*)&lA2s[row * 40 + kq * 8];
      int col = wx + d * 16 + m16;
      bb[d] = *(const bf16x8*)&lBs[col * 40 + kq * 8];
    }
    #pragma unroll
    for (int di = 0; di < 2; di++)
      #pragma unroll
      for (int dj = 0; dj < 2; dj++) {
        accR[di][dj] = MFMA16(a1[di], bb[dj], accR[di][dj], 0, 0, 0);
        accI[di][dj] = MFMA16(a2[di], bb[dj], accI[di][dj], 0, 0, 0);
      }
  }
  int n = b / CC;
  #pragma unroll
  for (int di = 0; di < 2; di++)
    #pragma unroll
    for (int dj = 0; dj < 2; dj++)
      #pragma unroll
      for (int r = 0; r < 4; r++) {
        int row = i0 + wy + di * 16 + kq * 4 + r;
        int col = j0 + wx + dj * 16 + m16;
        float vr = accR[di][dj][r], vi = accI[di][dj][r];
        size_t idx = (size_t)b * HW + row * WW + col;
        if (mode == 1) {
          float m = mask[n * HW + row * WW + col];
          vr = m * (vr - fdat[idx * 2]);
          vi = m * (vi - fdat[idx * 2 + 1]);
        }
        OutB[idx] = pack_bf(vr, vi);
      }
}

// ---------------- K6: coil-combine with conj(sens), bf16-pair input --------
__global__ void k_coilsum(const unsigned int* __restrict__ Z, const float* __restrict__ cs,
                          float* __restrict__ At) {
  int idx = blockIdx.x * blockDim.x + threadIdx.x;
  if (idx >= NN * HW) return;
  int n = idx / HW, hw = idx % HW;
  float ar = 0.f, ai = 0.f;
  for (int c = 0; c < CC; c++) {
    size_t zi = (size_t)(n * CC + c) * HW + hw;
    unsigned int p = Z[zi];
    float zr = b2f((unsigned short)(p & 0xffff));
    float zim = b2f((unsigned short)(p >> 16));
    float crr = cs[zi * 2], cii = cs[zi * 2 + 1];
    ar += zr * crr + zim * cii;
    ai += zim * crr - zr * cii;
  }
  At[idx * 2] = ar;
  At[idx * 2 + 1] = ai;
}

// ---------------- K7: out = u - sum(RuP)/FF - lamb*At ----------------------
__global__ void k_final(const float* __restrict__ u_t, const float* __restrict__ RuP,
                        const float* __restrict__ At, const float* __restrict__ lamb,
                        float* __restrict__ out) {
  int idx = blockIdx.x * blockDim.x + threadIdx.x;
  if (idx >= NN * HW * 2) return;
  float ru = RuP[idx] + RuP[idx + 819200] + RuP[idx + 2 * 819200] + RuP[idx + 3 * 819200];
  out[idx] = u_t[idx] - ru * (1.0f / (float)FF) - lamb[0] * At[idx];
}

extern "C" void kernel_launch(void* const* d_in, const int* in_sizes, int n_in,
                              void* d_out, int out_size, void* d_ws, size_t ws_size,
                              hipStream_t stream) {
  const float* u_t   = (const float*)d_in[0];
  const float* fdat  = (const float*)d_in[1];
  const float* cs    = (const float*)d_in[2];
  const float* mask  = (const float*)d_in[3];
  const float* ck    = (const float*)d_in[4];
  const float* w     = (const float*)d_in[5];
  const float* mu    = (const float*)d_in[6];
  const float* sigma = (const float*)d_in[7];
  const float* lamb  = (const float*)d_in[8];
  float* out = (float*)d_out;

  // ws layout (4-byte words):
  //  Fbf @0          102400
  //  Wpk @102400     5760
  //  At  @108160     819200
  //  RuP @927360     3276800
  //  big @4204160    12288000  (conv phase: fukb aliases here; DC: P | Q)
  unsigned int* wsw = (unsigned int*)d_ws;
  unsigned int* Fbf = wsw;
  unsigned int* Wpk = wsw + 102400;
  float* At  = (float*)(wsw + 108160);
  float* RuP = (float*)(wsw + 927360);
  unsigned int* big = wsw + 4204160;
  unsigned short* fukb = (unsigned short*)big;
  unsigned int* P = big;
  unsigned int* Q = big + 6144000;

  k_dft<<<(HW + 255) / 256, 256, 0, stream>>>(Fbf);
  k_prep<<<(32 * 176 + 255) / 256, 256, 0, stream>>>(ck, Wpk);
  k_conv_rbf_mfma<<<dim3(22, 22, NN), 256, 0, stream>>>(u_t, Wpk, w, mu, sigma, fukb);
  k_convT<<<dim3(10, 10, NN * 4), 256, 0, stream>>>(fukb, ck, RuP);
  k_umul<<<(NCB * HW + 255) / 256, 256, 0, stream>>>(u_t, cs, P);
  // NOTE: umul overwrites the fukb alias region only after convT completed (stream order)
  k_gemm<<<dim3(5, 5, NCB), 256, 0, stream>>>(Fbf, 0L, 0x80000000u, 0u,
                                              P, (long)HW, 0u,
                                              Q, 0, nullptr, nullptr);
  k_gemm<<<dim3(5, 5, NCB), 256, 0, stream>>>(Q, (long)HW, 0x80000000u, 0u,
                                              Fbf, 0L, 0u,
                                              P, 1, mask, fdat);
  k_gemm<<<dim3(5, 5, NCB), 256, 0, stream>>>(Fbf, 0L, 0u, 0x00008000u,
                                              P, (long)HW, 0u,
                                              Q, 0, nullptr, nullptr);
  k_gemm<<<dim3(5, 5, NCB), 256, 0, stream>>>(Q, (long)HW, 0x80000000u, 0u,
                                              Fbf, 0L, 0x80000000u,
                                              P, 0, nullptr, nullptr);
  k_coilsum<<<(NN * HW + 255) / 256, 256, 0, stream>>>(P, cs, At);
  k_final<<<(NN * HW * 2 + 255) / 256, 256, 0, stream>>>(u_t, RuP, At, lamb, out);
}

// Round 6
// 434.358 us; speedup vs baseline: 6.6288x; 1.1074x over previous
//
#include <hip/hip_runtime.h>
#include <hip/hip_bf16.h>
#include <math.h>

#define NN 4
#define CC 15
#define HH 320
#define WW 320
#define HW (HH*WW)          // 102400
#define FF 32
#define KS 11
#define PADN 11
#define CPAD 5
#define HP 342
#define NK 31
#define NCB (NN*CC)

typedef short bf16x8 __attribute__((ext_vector_type(8)));
typedef float f32x4 __attribute__((ext_vector_type(4)));
typedef unsigned short u16x4 __attribute__((ext_vector_type(4)));

#define MFMA16 __builtin_amdgcn_mfma_f32_16x16x32_bf16

__device__ __forceinline__ unsigned int pack_bf(float r, float i) {
  __hip_bfloat16 hr = __float2bfloat16(r), hi = __float2bfloat16(i);
  unsigned short ur = *(unsigned short*)&hr, ui = *(unsigned short*)&hi;
  return (unsigned int)ur | ((unsigned int)ui << 16);
}
__device__ __forceinline__ unsigned short f2b(float x) {
  __hip_bfloat16 h = __float2bfloat16(x);
  return *(unsigned short*)&h;
}
__device__ __forceinline__ float b2f(unsigned short u) {
  __hip_bfloat16 h = *(__hip_bfloat16*)&u;
  return __bfloat162float(h);
}

// ---------------- K0: centered orthonormal DFT matrix, bf16 pairs ----------
__global__ void k_dft(unsigned int* __restrict__ Fbf) {
  int idx = blockIdx.x * blockDim.x + threadIdx.x;
  if (idx >= HW) return;
  int k = idx / WW, n = idx % WW;
  int prod = (k - 160) * (n - 160);
  int r = prod % 320; if (r < 0) r += 320;
  float ang = -6.283185307179586f * (float)r / 320.0f;
  const float s = 0.05590169943749474f; // 1/sqrt(320)
  Fbf[idx] = pack_bf(cosf(ang) * s, sinf(ang) * s);
}

// ---------------- K0b: prepack conv weights (forward, A-operand) -----------
// Wpk[o][kw] u32, kw=0..175: ky=kw/16, kx=kw%16; bf16 pair (ch0,ch1); kx>10 -> 0
__global__ void k_prep(const float* __restrict__ ck, unsigned int* __restrict__ Wpk) {
  int idx = blockIdx.x * blockDim.x + threadIdx.x;
  if (idx >= 32 * 176) return;
  int o = idx / 176, kw = idx % 176;
  int ky = kw / 16, kx = kw % 16;
  unsigned int v = 0;
  if (kx <= 10) {
    const float* p = &ck[(o * 121 + ky * 11 + kx) * 2];
    v = pack_bf(p[0], p[1]);
  }
  Wpk[idx] = v;
}

// ---------------- K0c: prepack adjoint weights Wt[ch][kx][ky16][o32] -------
__global__ void k_prep2(const float* __restrict__ ck, unsigned short* __restrict__ Wt) {
  int idx = blockIdx.x * blockDim.x + threadIdx.x;
  if (idx >= 2 * 11 * 16 * 32) return;
  int o = idx & 31;
  int ky = (idx >> 5) & 15;
  int rest = idx >> 9;
  int kx = rest % 11, ch = rest / 11;
  unsigned short v = 0;
  if (ky <= 10) v = f2b(ck[(o * 121 + ky * 11 + kx) * 2 + ch]);
  Wt[idx] = v;
}

// ---------------- K2: conv(11x11) + RBF via MFMA implicit GEMM -------------
// block: 16y x 16x pixel tile, all 32 features; writes fukT[n][y][x][o] bf16
__global__ __launch_bounds__(256) void k_conv_rbf_mfma(
    const float* __restrict__ u_t, const unsigned int* __restrict__ Wpk,
    const float* __restrict__ w, const float* __restrict__ mu,
    const float* __restrict__ sigma, unsigned short* __restrict__ fukT) {
  __shared__ unsigned int lW[32 * 180];   // weights, row stride 180 dw
  __shared__ unsigned int tIn[26 * 32];   // input tile, (ch0,ch1) bf16 pairs
  __shared__ float wl[32 * 36];           // RBF weights, stride 36
  int n = blockIdx.z;
  int y0 = blockIdx.y * 16, x0 = blockIdx.x * 16;
  int tid = threadIdx.x;
  for (int i = tid; i < 32 * 176; i += 256)
    lW[(i / 176) * 180 + (i % 176)] = Wpk[i];
  for (int i = tid; i < 32 * 36; i += 256) {
    int idx = i % 36;
    wl[i] = (idx < 31) ? w[(i / 36) * 31 + idx] : 0.f;
  }
  for (int i = tid; i < 26 * 32; i += 256) {
    int rr = i >> 5, cc = i & 31;
    unsigned int v = 0;
    if (cc < 26) {
      int py = y0 + rr - 5, px = x0 + cc - 5;
      if (py >= 0 && py < HP && px >= 0 && px < HP) {
        int uy = py - PADN; uy = uy < 0 ? -uy : (uy >= HH ? 2 * (HH - 1) - uy : uy);
        int ux = px - PADN; ux = ux < 0 ? -ux : (ux >= WW ? 2 * (WW - 1) - ux : ux);
        const float* up = &u_t[((n * HH + uy) * WW + ux) * 2];
        v = pack_bf(up[0], up[1]);
      }
    }
    tIn[i] = v;
  }
  __syncthreads();
  int lane = tid & 63, wave = tid >> 6;
  int m16 = lane & 15, kq = lane >> 4;
  const short* lWs = (const short*)lW;
  f32x4 acc[4][2] = {};
  for (int ky = 0; ky < 11; ky++) {
    bf16x8 af0 = *(const bf16x8*)&lWs[m16 * 360 + ky * 32 + kq * 8];
    bf16x8 af1 = *(const bf16x8*)&lWs[(m16 + 16) * 360 + ky * 32 + kq * 8];
    #pragma unroll
    for (int nt = 0; nt < 4; nt++) {
      int rr = wave * 4 + nt + ky;
      int c0 = rr * 32 + m16 + kq * 4;
      union { unsigned int u[4]; bf16x8 v; } bu;
      bu.u[0] = tIn[c0]; bu.u[1] = tIn[c0 + 1];
      bu.u[2] = tIn[c0 + 2]; bu.u[3] = tIn[c0 + 3];
      acc[nt][0] = MFMA16(af0, bu.v, acc[nt][0], 0, 0, 0);
      acc[nt][1] = MFMA16(af1, bu.v, acc[nt][1], 0, 0, 0);
    }
  }
  // RBF epilogue + transposed store. C layout: col=lane&15 (x), row=kq*4+r (o)
  float mu0 = mu[0];
  float dmu = mu[1] - mu[0];
  float invD = 1.0f / dmu;
  float sg = sigma[0];
  float nInv = -1.0f / (2.0f * sg * sg);
  #pragma unroll
  for (int nt = 0; nt < 4; nt++) {
    int Y = y0 + wave * 4 + nt;
    int X = x0 + m16;
    if (Y >= HP || X >= HP) continue;
    #pragma unroll
    for (int mt = 0; mt < 2; mt++) {
      u16x4 pk;
      #pragma unroll
      for (int r = 0; r < 4; r++) {
        float v = acc[nt][mt][r];
        int o = mt * 16 + kq * 4 + r;
        float cf = fminf(fmaxf(rintf((v - mu0) * invD), 0.f), 30.f);
        int i0a = ((int)cf - 5) & ~3;
        if (i0a < 0) i0a = 0; if (i0a > 20) i0a = 20;
        const f32x4* wp = (const f32x4*)&wl[o * 36 + i0a];
        f32x4 w0 = wp[0], w1 = wp[1], w2 = wp[2];
        float base = mu0 + (float)i0a * dmu;
        float res = 0.f;
        #pragma unroll
        for (int ii = 0; ii < 12; ii++) {
          float d = v - (base + (float)ii * dmu);
          float wv = (ii < 4) ? w0[ii] : (ii < 8) ? w1[ii - 4] : w2[ii - 8];
          res += wv * __expf(d * d * nInv);
        }
        pk[r] = f2b(res);
      }
      *(u16x4*)&fukT[(((size_t)n * HP + Y) * HP + X) * 32 + mt * 16 + kq * 4] = pk;
    }
  }
}

// ---------------- K3: transposed conv via MFMA -----------------------------
// block: 16y x 32x output tile. waves: (ch, x-half). M=ky(16,11 used), N=16x,
// K=32 features per kx-block. Scatter-accumulate by output row into LDS.
__global__ __launch_bounds__(256) void k_convT_mfma(
    const unsigned short* __restrict__ fukT, const unsigned short* __restrict__ Wt,
    float* __restrict__ Ru) {
  __shared__ unsigned short rowBuf[42 * 32];  // 2688 B
  __shared__ float accS[16 * 67];             // 4288 B
  int n = blockIdx.z;
  int y0 = blockIdx.y * 16, x0 = blockIdx.x * 32;
  int tid = threadIdx.x;
  int lane = tid & 63, wave = tid >> 6;
  int ch = wave >> 1, xh = wave & 1;
  int m16 = lane & 15, kq = lane >> 4;
  bf16x8 afr[11];
  #pragma unroll
  for (int kx = 0; kx < 11; kx++)
    afr[kx] = *(const bf16x8*)&Wt[((ch * 11 + kx) * 16 + m16) * 32 + kq * 8];
  for (int i = tid; i < 16 * 67; i += 256) accS[i] = 0.f;
  int xl = xh * 16 + m16;                     // local x 0..31
  for (int t = 0; t < 26; t++) {
    int r = y0 + 6 + t;
    __syncthreads();
    {
      const unsigned int* src = (const unsigned int*)&fukT[(((size_t)n * HP + r) * HP + x0 + 6) * 32];
      unsigned int* dst = (unsigned int*)rowBuf;
      for (int i = tid; i < 42 * 16; i += 256) dst[i] = src[i];
    }
    __syncthreads();
    f32x4 dacc = {};
    #pragma unroll
    for (int kx = 0; kx < 11; kx++) {
      bf16x8 bfrag = *(const bf16x8*)&rowBuf[(xl + 10 - kx) * 32 + kq * 8];
      dacc = MFMA16(afr[kx], bfrag, dacc, 0, 0, 0);
    }
    #pragma unroll
    for (int rg = 0; rg < 4; rg++) {
      int ky = kq * 4 + rg;
      int y = t + ky - 10;
      if (ky <= 10 && y >= 0 && y < 16)
        accS[y * 67 + xl * 2 + ch] += dacc[rg];
    }
  }
  __syncthreads();
  int chO = tid & 1, xO = (tid >> 1) & 31, yb = tid >> 6;
  #pragma unroll
  for (int q = 0; q < 4; q++) {
    int y = yb + q * 4;
    Ru[(((size_t)n * HH + y0 + y) * WW + x0 + xO) * 2 + chO] = accS[y * 67 + xO * 2 + chO];
  }
}

// ---------------- K4: X0 = u * coil_sens (complex), bf16 pairs -------------
__global__ void k_umul(const float* __restrict__ u_t, const float* __restrict__ cs,
                       unsigned int* __restrict__ X0) {
  int idx = blockIdx.x * blockDim.x + threadIdx.x;
  if (idx >= NCB * HW) return;
  int hw = idx % HW;
  int n = (idx / HW) / CC;
  float ur = u_t[(n * HW + hw) * 2], ui = u_t[(n * HW + hw) * 2 + 1];
  float cr = cs[idx * 2], ci = cs[idx * 2 + 1];
  X0[idx] = pack_bf(ur * cr - ui * ci, ur * ci + ui * cr);
}

// ---------------- K5: batched complex GEMM via bf16 MFMA -------------------
__global__ __launch_bounds__(256) void k_gemm(
    const unsigned int* __restrict__ Abase, long aStride,
    unsigned int xorA1, unsigned int xorA2,
    const unsigned int* __restrict__ Bbase, long bStride, unsigned int xorB,
    unsigned int* __restrict__ OutB, int mode,
    const float* __restrict__ mask, const float* __restrict__ fdat) {
  __shared__ unsigned int lA1[64 * 20], lA2[64 * 20], lB[64 * 20];
  int b = blockIdx.z;
  int i0 = blockIdx.y * 64, j0 = blockIdx.x * 64;
  const unsigned int* A = Abase + (size_t)b * aStride;
  const unsigned int* B = Bbase + (size_t)b * bStride;
  int tid = threadIdx.x;
  int lane = tid & 63, wave = tid >> 6;
  int wy = (wave >> 1) * 32, wx = (wave & 1) * 32;
  int m16 = lane & 15, kq = lane >> 4;
  f32x4 accR[2][2] = {}, accI[2][2] = {};
  int ar = tid >> 4, akc = tid & 15;
  int bj = tid & 63, bk0 = tid >> 6;
  const short* lA1s = (const short*)lA1;
  const short* lA2s = (const short*)lA2;
  const short* lBs  = (const short*)lB;
  for (int kc0 = 0; kc0 < WW; kc0 += 16) {
    __syncthreads();
    #pragma unroll
    for (int it = 0; it < 4; it++) {
      int r = ar + 16 * it;
      unsigned int p = A[(i0 + r) * WW + kc0 + akc];
      lA1[r * 20 + akc] = p ^ xorA1;
      lA2[r * 20 + akc] = ((p >> 16) | (p << 16)) ^ xorA2;
    }
    #pragma unroll
    for (int it = 0; it < 4; it++) {
      int kc = bk0 + 4 * it;
      unsigned int p = B[(kc0 + kc) * WW + j0 + bj];
      lB[bj * 20 + kc] = p ^ xorB;
    }
    __syncthreads();
    bf16x8 a1[2], a2[2], bb[2];
    #pragma unroll
    for (int d = 0; d < 2; d++) {
      int row = wy + d * 16 + m16;
      a1[d] = *(const bf16x8*)&lA1s[row * 40 + kq * 8];
      a2[d] = *(const bf16x8*)&lA2s[row * 40 + kq * 8];
      int col = wx + d * 16 + m16;
      bb[d] = *(const bf16x8*)&lBs[col * 40 + kq * 8];
    }
    #pragma unroll
    for (int di = 0; di < 2; di++)
      #pragma unroll
      for (int dj = 0; dj < 2; dj++) {
        accR[di][dj] = MFMA16(a1[di], bb[dj], accR[di][dj], 0, 0, 0);
        accI[di][dj] = MFMA16(a2[di], bb[dj], accI[di][dj], 0, 0, 0);
      }
  }
  int n = b / CC;
  #pragma unroll
  for (int di = 0; di < 2; di++)
    #pragma unroll
    for (int dj = 0; dj < 2; dj++)
      #pragma unroll
      for (int r = 0; r < 4; r++) {
        int row = i0 + wy + di * 16 + kq * 4 + r;
        int col = j0 + wx + dj * 16 + m16;
        float vr = accR[di][dj][r], vi = accI[di][dj][r];
        size_t idx = (size_t)b * HW + row * WW + col;
        if (mode == 1) {
          float m = mask[n * HW + row * WW + col];
          vr = m * (vr - fdat[idx * 2]);
          vi = m * (vi - fdat[idx * 2 + 1]);
        }
        OutB[idx] = pack_bf(vr, vi);
      }
}

// ---------------- K6: coil-combine with conj(sens), bf16-pair input --------
__global__ void k_coilsum(const unsigned int* __restrict__ Z, const float* __restrict__ cs,
                          float* __restrict__ At) {
  int idx = blockIdx.x * blockDim.x + threadIdx.x;
  if (idx >= NN * HW) return;
  int n = idx / HW, hw = idx % HW;
  float ar = 0.f, ai = 0.f;
  for (int c = 0; c < CC; c++) {
    size_t zi = (size_t)(n * CC + c) * HW + hw;
    unsigned int p = Z[zi];
    float zr = b2f((unsigned short)(p & 0xffff));
    float zim = b2f((unsigned short)(p >> 16));
    float crr = cs[zi * 2], cii = cs[zi * 2 + 1];
    ar += zr * crr + zim * cii;
    ai += zim * crr - zr * cii;
  }
  At[idx * 2] = ar;
  At[idx * 2 + 1] = ai;
}

// ---------------- K7: out = u - Ru/FF - lamb*At ----------------------------
__global__ void k_final(const float* __restrict__ u_t, const float* __restrict__ Ru,
                        const float* __restrict__ At, const float* __restrict__ lamb,
                        float* __restrict__ out) {
  int idx = blockIdx.x * blockDim.x + threadIdx.x;
  if (idx >= NN * HW * 2) return;
  out[idx] = u_t[idx] - Ru[idx] * (1.0f / (float)FF) - lamb[0] * At[idx];
}

extern "C" void kernel_launch(void* const* d_in, const int* in_sizes, int n_in,
                              void* d_out, int out_size, void* d_ws, size_t ws_size,
                              hipStream_t stream) {
  const float* u_t   = (const float*)d_in[0];
  const float* fdat  = (const float*)d_in[1];
  const float* cs    = (const float*)d_in[2];
  const float* mask  = (const float*)d_in[3];
  const float* ck    = (const float*)d_in[4];
  const float* w     = (const float*)d_in[5];
  const float* mu    = (const float*)d_in[6];
  const float* sigma = (const float*)d_in[7];
  const float* lamb  = (const float*)d_in[8];
  float* out = (float*)d_out;

  // ws layout (u32 words):
  //  Fbf @0         102400
  //  Wpk @102400    5760
  //  Wt  @108160    5632
  //  At  @113792    819200
  //  Ru  @932992    819200
  //  big @1752192   12288000  (conv phase: fukT [7486848 w]; DC: P | Q)
  unsigned int* wsw = (unsigned int*)d_ws;
  unsigned int* Fbf = wsw;
  unsigned int* Wpk = wsw + 102400;
  unsigned short* Wt = (unsigned short*)(wsw + 108160);
  float* At = (float*)(wsw + 113792);
  float* Ru = (float*)(wsw + 932992);
  unsigned int* big = wsw + 1752192;
  unsigned short* fukT = (unsigned short*)big;
  unsigned int* P = big;
  unsigned int* Q = big + 6144000;

  k_dft<<<(HW + 255) / 256, 256, 0, stream>>>(Fbf);
  k_prep<<<(32 * 176 + 255) / 256, 256, 0, stream>>>(ck, Wpk);
  k_prep2<<<(2 * 11 * 16 * 32 + 255) / 256, 256, 0, stream>>>(ck, Wt);
  k_conv_rbf_mfma<<<dim3(22, 22, NN), 256, 0, stream>>>(u_t, Wpk, w, mu, sigma, fukT);
  k_convT_mfma<<<dim3(10, 20, NN), 256, 0, stream>>>(fukT, Wt, Ru);
  k_umul<<<(NCB * HW + 255) / 256, 256, 0, stream>>>(u_t, cs, P);
  // NOTE: umul overwrites the fukT alias region only after convT completed (stream order)
  k_gemm<<<dim3(5, 5, NCB), 256, 0, stream>>>(Fbf, 0L, 0x80000000u, 0u,
                                              P, (long)HW, 0u,
                                              Q, 0, nullptr, nullptr);
  k_gemm<<<dim3(5, 5, NCB), 256, 0, stream>>>(Q, (long)HW, 0x80000000u, 0u,
                                              Fbf, 0L, 0u,
                                              P, 1, mask, fdat);
  k_gemm<<<dim3(5, 5, NCB), 256, 0, stream>>>(Fbf, 0L, 0u, 0x00008000u,
                                              P, (long)HW, 0u,
                                              Q, 0, nullptr, nullptr);
  k_gemm<<<dim3(5, 5, NCB), 256, 0, stream>>>(Q, (long)HW, 0x80000000u, 0u,
                                              Fbf, 0L, 0x80000000u,
                                              P, 0, nullptr, nullptr);
  k_coilsum<<<(NN * HW + 255) / 256, 256, 0, stream>>>(P, cs, At);
  k_final<<<(NN * HW * 2 + 255) / 256, 256, 0, stream>>>(u_t, Ru, At, lamb, out);
}

// Round 7
// 386.808 us; speedup vs baseline: 7.4437x; 1.1229x over previous
//
#include <hip/hip_runtime.h>
#include <hip/hip_bf16.h>
#include <math.h>

#define NN 4
#define CC 15
#define HH 320
#define WW 320
#define HW (HH*WW)          // 102400
#define FF 32
#define KS 11
#define PADN 11
#define CPAD 5
#define HP 342
#define NK 31
#define NCB (NN*CC)

typedef short bf16x8 __attribute__((ext_vector_type(8)));
typedef float f32x4 __attribute__((ext_vector_type(4)));
typedef unsigned short u16x4 __attribute__((ext_vector_type(4)));

#define MFMA16 __builtin_amdgcn_mfma_f32_16x16x32_bf16

__device__ __forceinline__ unsigned int pack_bf(float r, float i) {
  __hip_bfloat16 hr = __float2bfloat16(r), hi = __float2bfloat16(i);
  unsigned short ur = *(unsigned short*)&hr, ui = *(unsigned short*)&hi;
  return (unsigned int)ur | ((unsigned int)ui << 16);
}
__device__ __forceinline__ unsigned short f2b(float x) {
  __hip_bfloat16 h = __float2bfloat16(x);
  return *(unsigned short*)&h;
}
__device__ __forceinline__ float b2f(unsigned short u) {
  __hip_bfloat16 h = *(__hip_bfloat16*)&u;
  return __bfloat162float(h);
}
__device__ __forceinline__ unsigned int rot16(unsigned int x) {
  return (x >> 16) | (x << 16);
}

// ---------------- K0: centered orthonormal DFT matrix, bf16 pairs ----------
__global__ void k_dft(unsigned int* __restrict__ Fbf) {
  int idx = blockIdx.x * blockDim.x + threadIdx.x;
  if (idx >= HW) return;
  int k = idx / WW, n = idx % WW;
  int prod = (k - 160) * (n - 160);
  int r = prod % 320; if (r < 0) r += 320;
  float ang = -6.283185307179586f * (float)r / 320.0f;
  const float s = 0.05590169943749474f; // 1/sqrt(320)
  Fbf[idx] = pack_bf(cosf(ang) * s, sinf(ang) * s);
}

// ---------------- K0b: prepack conv weights (forward, A-operand) -----------
__global__ void k_prep(const float* __restrict__ ck, unsigned int* __restrict__ Wpk) {
  int idx = blockIdx.x * blockDim.x + threadIdx.x;
  if (idx >= 32 * 176) return;
  int o = idx / 176, kw = idx % 176;
  int ky = kw / 16, kx = kw % 16;
  unsigned int v = 0;
  if (kx <= 10) {
    const float* p = &ck[(o * 121 + ky * 11 + kx) * 2];
    v = pack_bf(p[0], p[1]);
  }
  Wpk[idx] = v;
}

// ---------------- K0c: prepack adjoint weights Wt[ch][kx][ky16][o32] -------
__global__ void k_prep2(const float* __restrict__ ck, unsigned short* __restrict__ Wt) {
  int idx = blockIdx.x * blockDim.x + threadIdx.x;
  if (idx >= 2 * 11 * 16 * 32) return;
  int o = idx & 31;
  int ky = (idx >> 5) & 15;
  int rest = idx >> 9;
  int kx = rest % 11, ch = rest / 11;
  unsigned short v = 0;
  if (ky <= 10) v = f2b(ck[(o * 121 + ky * 11 + kx) * 2 + ch]);
  Wt[idx] = v;
}

// ---------------- K2: conv(11x11) + RBF via MFMA implicit GEMM -------------
__global__ __launch_bounds__(256) void k_conv_rbf_mfma(
    const float* __restrict__ u_t, const unsigned int* __restrict__ Wpk,
    const float* __restrict__ w, const float* __restrict__ mu,
    const float* __restrict__ sigma, unsigned short* __restrict__ fukT) {
  __shared__ unsigned int lW[32 * 180];
  __shared__ unsigned int tIn[26 * 32];
  __shared__ float wl[32 * 36];
  int n = blockIdx.z;
  int y0 = blockIdx.y * 16, x0 = blockIdx.x * 16;
  int tid = threadIdx.x;
  for (int i = tid; i < 32 * 176; i += 256)
    lW[(i / 176) * 180 + (i % 176)] = Wpk[i];
  for (int i = tid; i < 32 * 36; i += 256) {
    int idx = i % 36;
    wl[i] = (idx < 31) ? w[(i / 36) * 31 + idx] : 0.f;
  }
  for (int i = tid; i < 26 * 32; i += 256) {
    int rr = i >> 5, cc = i & 31;
    unsigned int v = 0;
    if (cc < 26) {
      int py = y0 + rr - 5, px = x0 + cc - 5;
      if (py >= 0 && py < HP && px >= 0 && px < HP) {
        int uy = py - PADN; uy = uy < 0 ? -uy : (uy >= HH ? 2 * (HH - 1) - uy : uy);
        int ux = px - PADN; ux = ux < 0 ? -ux : (ux >= WW ? 2 * (WW - 1) - ux : ux);
        const float* up = &u_t[((n * HH + uy) * WW + ux) * 2];
        v = pack_bf(up[0], up[1]);
      }
    }
    tIn[i] = v;
  }
  __syncthreads();
  int lane = tid & 63, wave = tid >> 6;
  int m16 = lane & 15, kq = lane >> 4;
  const short* lWs = (const short*)lW;
  f32x4 acc[4][2] = {};
  for (int ky = 0; ky < 11; ky++) {
    bf16x8 af0 = *(const bf16x8*)&lWs[m16 * 360 + ky * 32 + kq * 8];
    bf16x8 af1 = *(const bf16x8*)&lWs[(m16 + 16) * 360 + ky * 32 + kq * 8];
    #pragma unroll
    for (int nt = 0; nt < 4; nt++) {
      int rr = wave * 4 + nt + ky;
      int c0 = rr * 32 + m16 + kq * 4;
      union { unsigned int u[4]; bf16x8 v; } bu;
      bu.u[0] = tIn[c0]; bu.u[1] = tIn[c0 + 1];
      bu.u[2] = tIn[c0 + 2]; bu.u[3] = tIn[c0 + 3];
      acc[nt][0] = MFMA16(af0, bu.v, acc[nt][0], 0, 0, 0);
      acc[nt][1] = MFMA16(af1, bu.v, acc[nt][1], 0, 0, 0);
    }
  }
  float mu0 = mu[0];
  float dmu = mu[1] - mu[0];
  float invD = 1.0f / dmu;
  float sg = sigma[0];
  float nInv = -1.0f / (2.0f * sg * sg);
  #pragma unroll
  for (int nt = 0; nt < 4; nt++) {
    int Y = y0 + wave * 4 + nt;
    int X = x0 + m16;
    if (Y >= HP || X >= HP) continue;
    #pragma unroll
    for (int mt = 0; mt < 2; mt++) {
      u16x4 pk;
      #pragma unroll
      for (int r = 0; r < 4; r++) {
        float v = acc[nt][mt][r];
        int o = mt * 16 + kq * 4 + r;
        float cf = fminf(fmaxf(rintf((v - mu0) * invD), 0.f), 30.f);
        int i0a = ((int)cf - 5) & ~3;
        if (i0a < 0) i0a = 0; if (i0a > 20) i0a = 20;
        const f32x4* wp = (const f32x4*)&wl[o * 36 + i0a];
        f32x4 w0 = wp[0], w1 = wp[1], w2 = wp[2];
        float base = mu0 + (float)i0a * dmu;
        float res = 0.f;
        #pragma unroll
        for (int ii = 0; ii < 12; ii++) {
          float d = v - (base + (float)ii * dmu);
          float wv = (ii < 4) ? w0[ii] : (ii < 8) ? w1[ii - 4] : w2[ii - 8];
          res += wv * __expf(d * d * nInv);
        }
        pk[r] = f2b(res);
      }
      *(u16x4*)&fukT[(((size_t)n * HP + Y) * HP + X) * 32 + mt * 16 + kq * 4] = pk;
    }
  }
}

// ---------------- K3: transposed conv via MFMA -----------------------------
__global__ __launch_bounds__(256) void k_convT_mfma(
    const unsigned short* __restrict__ fukT, const unsigned short* __restrict__ Wt,
    float* __restrict__ Ru) {
  __shared__ unsigned short rowBuf[42 * 32];
  __shared__ float accS[16 * 67];
  int n = blockIdx.z;
  int y0 = blockIdx.y * 16, x0 = blockIdx.x * 32;
  int tid = threadIdx.x;
  int lane = tid & 63, wave = tid >> 6;
  int ch = wave >> 1, xh = wave & 1;
  int m16 = lane & 15, kq = lane >> 4;
  bf16x8 afr[11];
  #pragma unroll
  for (int kx = 0; kx < 11; kx++)
    afr[kx] = *(const bf16x8*)&Wt[((ch * 11 + kx) * 16 + m16) * 32 + kq * 8];
  for (int i = tid; i < 16 * 67; i += 256) accS[i] = 0.f;
  int xl = xh * 16 + m16;
  for (int t = 0; t < 26; t++) {
    int r = y0 + 6 + t;
    __syncthreads();
    {
      const unsigned int* src = (const unsigned int*)&fukT[(((size_t)n * HP + r) * HP + x0 + 6) * 32];
      unsigned int* dst = (unsigned int*)rowBuf;
      for (int i = tid; i < 42 * 16; i += 256) dst[i] = src[i];
    }
    __syncthreads();
    f32x4 dacc = {};
    #pragma unroll
    for (int kx = 0; kx < 11; kx++) {
      bf16x8 bfrag = *(const bf16x8*)&rowBuf[(xl + 10 - kx) * 32 + kq * 8];
      dacc = MFMA16(afr[kx], bfrag, dacc, 0, 0, 0);
    }
    #pragma unroll
    for (int rg = 0; rg < 4; rg++) {
      int ky = kq * 4 + rg;
      int y = t + ky - 10;
      if (ky <= 10 && y >= 0 && y < 16)
        accS[y * 67 + xl * 2 + ch] += dacc[rg];
    }
  }
  __syncthreads();
  int chO = tid & 1, xO = (tid >> 1) & 31, yb = tid >> 6;
  #pragma unroll
  for (int q = 0; q < 4; q++) {
    int y = yb + q * 4;
    Ru[(((size_t)n * HH + y0 + y) * WW + x0 + xO) * 2 + chO] = accS[y * 67 + xO * 2 + chO];
  }
}

// ---------------- K4: X0 = u * coil_sens (complex), bf16 pairs -------------
__global__ void k_umul(const float* __restrict__ u_t, const float* __restrict__ cs,
                       unsigned int* __restrict__ X0) {
  int idx = blockIdx.x * blockDim.x + threadIdx.x;
  if (idx >= NCB * HW) return;
  int hw = idx % HW;
  int n = (idx / HW) / CC;
  float ur = u_t[(n * HW + hw) * 2], ui = u_t[(n * HW + hw) * 2 + 1];
  float cr = cs[idx * 2], ci = cs[idx * 2 + 1];
  X0[idx] = pack_bf(ur * cr - ui * ci, ur * ci + ui * cr);
}

// ---------------- K5: batched complex GEMM via bf16 MFMA (v2) --------------
// Raw A staged once (lA[64][36]); A1/A2 derived in registers (xor / rot16).
// B staged transposed lB[32 kc][68 col] — lane-consecutive writes.
// K-chunk = 32 u32 (K=64), 10 iterations, register prefetch of next tile.
__global__ __launch_bounds__(256) void k_gemm(
    const unsigned int* __restrict__ Abase, long aStride,
    unsigned int xorA1, unsigned int xorA2,
    const unsigned int* __restrict__ Bbase, long bStride, unsigned int xorB,
    unsigned int* __restrict__ OutB, int mode,
    const float* __restrict__ mask, const float* __restrict__ fdat) {
  __shared__ unsigned int lA[64 * 36];
  __shared__ unsigned int lB[32 * 68];
  int b = blockIdx.z;
  int i0 = blockIdx.y * 64, j0 = blockIdx.x * 64;
  const unsigned int* A = Abase + (size_t)b * aStride;
  const unsigned int* B = Bbase + (size_t)b * bStride;
  int tid = threadIdx.x;
  int lane = tid & 63, wave = tid >> 6;
  int wy = (wave >> 1) * 32, wx = (wave & 1) * 32;
  int m16 = lane & 15, kq = lane >> 4;
  f32x4 accR[2][2] = {}, accI[2][2] = {};
  int ar = tid >> 3;          // 0..31: rows ar, ar+32
  int ag = tid & 7;           // col group of 4 u32
  int bkc = tid >> 4;         // 0..15: rows bkc, bkc+16
  int bc = (tid & 15) * 4;    // col group of 4
  uint4 pa0, pa1, pb0, pb1;
  pa0 = *(const uint4*)&A[(i0 + ar) * WW + ag * 4];
  pa1 = *(const uint4*)&A[(i0 + ar + 32) * WW + ag * 4];
  pb0 = *(const uint4*)&B[bkc * WW + j0 + bc];
  pb1 = *(const uint4*)&B[(bkc + 16) * WW + j0 + bc];
  for (int it = 0; it < 10; it++) {
    __syncthreads();
    *(uint4*)&lA[ar * 36 + ag * 4] = pa0;
    *(uint4*)&lA[(ar + 32) * 36 + ag * 4] = pa1;
    *(uint4*)&lB[bkc * 68 + bc] = pb0;
    *(uint4*)&lB[(bkc + 16) * 68 + bc] = pb1;
    __syncthreads();
    if (it < 9) {
      int kc0 = (it + 1) * 32;
      pa0 = *(const uint4*)&A[(i0 + ar) * WW + kc0 + ag * 4];
      pa1 = *(const uint4*)&A[(i0 + ar + 32) * WW + kc0 + ag * 4];
      pb0 = *(const uint4*)&B[(kc0 + bkc) * WW + j0 + bc];
      pb1 = *(const uint4*)&B[(kc0 + bkc + 16) * WW + j0 + bc];
    }
    #pragma unroll
    for (int s = 0; s < 2; s++) {
      bf16x8 a1[2], a2[2], bb[2];
      #pragma unroll
      for (int d = 0; d < 2; d++) {
        int row = wy + d * 16 + m16;
        uint4 p = *(const uint4*)&lA[row * 36 + s * 16 + kq * 4];
        union { unsigned int u[4]; bf16x8 v; } ua, ur2, ub;
        ua.u[0] = p.x ^ xorA1; ua.u[1] = p.y ^ xorA1;
        ua.u[2] = p.z ^ xorA1; ua.u[3] = p.w ^ xorA1;
        a1[d] = ua.v;
        ur2.u[0] = rot16(p.x) ^ xorA2; ur2.u[1] = rot16(p.y) ^ xorA2;
        ur2.u[2] = rot16(p.z) ^ xorA2; ur2.u[3] = rot16(p.w) ^ xorA2;
        a2[d] = ur2.v;
        int col = wx + d * 16 + m16;
        #pragma unroll
        for (int j2 = 0; j2 < 4; j2++)
          ub.u[j2] = lB[(s * 16 + kq * 4 + j2) * 68 + col] ^ xorB;
        bb[d] = ub.v;
      }
      #pragma unroll
      for (int di = 0; di < 2; di++)
        #pragma unroll
        for (int dj = 0; dj < 2; dj++) {
          accR[di][dj] = MFMA16(a1[di], bb[dj], accR[di][dj], 0, 0, 0);
          accI[di][dj] = MFMA16(a2[di], bb[dj], accI[di][dj], 0, 0, 0);
        }
    }
  }
  int n = b / CC;
  #pragma unroll
  for (int di = 0; di < 2; di++)
    #pragma unroll
    for (int dj = 0; dj < 2; dj++)
      #pragma unroll
      for (int r = 0; r < 4; r++) {
        int row = i0 + wy + di * 16 + kq * 4 + r;
        int col = j0 + wx + dj * 16 + m16;
        float vr = accR[di][dj][r], vi = accI[di][dj][r];
        size_t idx = (size_t)b * HW + row * WW + col;
        if (mode == 1) {
          float m = mask[n * HW + row * WW + col];
          vr = m * (vr - fdat[idx * 2]);
          vi = m * (vi - fdat[idx * 2 + 1]);
        }
        OutB[idx] = pack_bf(vr, vi);
      }
}

// ---------------- K6: coil-combine with conj(sens), bf16-pair input --------
__global__ void k_coilsum(const unsigned int* __restrict__ Z, const float* __restrict__ cs,
                          float* __restrict__ At) {
  int idx = blockIdx.x * blockDim.x + threadIdx.x;
  if (idx >= NN * HW) return;
  int n = idx / HW, hw = idx % HW;
  float ar = 0.f, ai = 0.f;
  for (int c = 0; c < CC; c++) {
    size_t zi = (size_t)(n * CC + c) * HW + hw;
    unsigned int p = Z[zi];
    float zr = b2f((unsigned short)(p & 0xffff));
    float zim = b2f((unsigned short)(p >> 16));
    float crr = cs[zi * 2], cii = cs[zi * 2 + 1];
    ar += zr * crr + zim * cii;
    ai += zim * crr - zr * cii;
  }
  At[idx * 2] = ar;
  At[idx * 2 + 1] = ai;
}

// ---------------- K7: out = u - Ru/FF - lamb*At ----------------------------
__global__ void k_final(const float* __restrict__ u_t, const float* __restrict__ Ru,
                        const float* __restrict__ At, const float* __restrict__ lamb,
                        float* __restrict__ out) {
  int idx = blockIdx.x * blockDim.x + threadIdx.x;
  if (idx >= NN * HW * 2) return;
  out[idx] = u_t[idx] - Ru[idx] * (1.0f / (float)FF) - lamb[0] * At[idx];
}

extern "C" void kernel_launch(void* const* d_in, const int* in_sizes, int n_in,
                              void* d_out, int out_size, void* d_ws, size_t ws_size,
                              hipStream_t stream) {
  const float* u_t   = (const float*)d_in[0];
  const float* fdat  = (const float*)d_in[1];
  const float* cs    = (const float*)d_in[2];
  const float* mask  = (const float*)d_in[3];
  const float* ck    = (const float*)d_in[4];
  const float* w     = (const float*)d_in[5];
  const float* mu    = (const float*)d_in[6];
  const float* sigma = (const float*)d_in[7];
  const float* lamb  = (const float*)d_in[8];
  float* out = (float*)d_out;

  unsigned int* wsw = (unsigned int*)d_ws;
  unsigned int* Fbf = wsw;
  unsigned int* Wpk = wsw + 102400;
  unsigned short* Wt = (unsigned short*)(wsw + 108160);
  float* At = (float*)(wsw + 113792);
  float* Ru = (float*)(wsw + 932992);
  unsigned int* big = wsw + 1752192;
  unsigned short* fukT = (unsigned short*)big;
  unsigned int* P = big;
  unsigned int* Q = big + 6144000;

  k_dft<<<(HW + 255) / 256, 256, 0, stream>>>(Fbf);
  k_prep<<<(32 * 176 + 255) / 256, 256, 0, stream>>>(ck, Wpk);
  k_prep2<<<(2 * 11 * 16 * 32 + 255) / 256, 256, 0, stream>>>(ck, Wt);
  k_conv_rbf_mfma<<<dim3(22, 22, NN), 256, 0, stream>>>(u_t, Wpk, w, mu, sigma, fukT);
  k_convT_mfma<<<dim3(10, 20, NN), 256, 0, stream>>>(fukT, Wt, Ru);
  k_umul<<<(NCB * HW + 255) / 256, 256, 0, stream>>>(u_t, cs, P);
  k_gemm<<<dim3(5, 5, NCB), 256, 0, stream>>>(Fbf, 0L, 0x80000000u, 0u,
                                              P, (long)HW, 0u,
                                              Q, 0, nullptr, nullptr);
  k_gemm<<<dim3(5, 5, NCB), 256, 0, stream>>>(Q, (long)HW, 0x80000000u, 0u,
                                              Fbf, 0L, 0u,
                                              P, 1, mask, fdat);
  k_gemm<<<dim3(5, 5, NCB), 256, 0, stream>>>(Fbf, 0L, 0u, 0x00008000u,
                                              P, (long)HW, 0u,
                                              Q, 0, nullptr, nullptr);
  k_gemm<<<dim3(5, 5, NCB), 256, 0, stream>>>(Q, (long)HW, 0x80000000u, 0u,
                                              Fbf, 0L, 0x80000000u,
                                              P, 0, nullptr, nullptr);
  k_coilsum<<<(NN * HW + 255) / 256, 256, 0, stream>>>(P, cs, At);
  k_final<<<(NN * HW * 2 + 255) / 256, 256, 0, stream>>>(u_t, Ru, At, lamb, out);
}

// Round 8
// 372.908 us; speedup vs baseline: 7.7212x; 1.0373x over previous
//
#include <hip/hip_runtime.h>
#include <hip/hip_bf16.h>
#include <math.h>

#define NN 4
#define CC 15
#define HH 320
#define WW 320
#define HW (HH*WW)          // 102400
#define FF 32
#define KS 11
#define PADN 11
#define CPAD 5
#define HP 342
#define NK 31
#define NCB (NN*CC)
#define TABN 256            // intervals; 257 entries, stride 260

typedef short bf16x8 __attribute__((ext_vector_type(8)));
typedef float f32x4 __attribute__((ext_vector_type(4)));
typedef unsigned short u16x4 __attribute__((ext_vector_type(4)));

#define MFMA16 __builtin_amdgcn_mfma_f32_16x16x32_bf16

__device__ __forceinline__ unsigned int pack_bf(float r, float i) {
  __hip_bfloat16 hr = __float2bfloat16(r), hi = __float2bfloat16(i);
  unsigned short ur = *(unsigned short*)&hr, ui = *(unsigned short*)&hi;
  return (unsigned int)ur | ((unsigned int)ui << 16);
}
__device__ __forceinline__ unsigned short f2b(float x) {
  __hip_bfloat16 h = __float2bfloat16(x);
  return *(unsigned short*)&h;
}
__device__ __forceinline__ float b2f(unsigned short u) {
  __hip_bfloat16 h = *(__hip_bfloat16*)&u;
  return __bfloat162float(h);
}
__device__ __forceinline__ unsigned int rot16(unsigned int x) {
  return (x >> 16) | (x << 16);
}

// ---------------- K0: centered orthonormal DFT matrix, bf16 pairs ----------
__global__ void k_dft(unsigned int* __restrict__ Fbf) {
  int idx = blockIdx.x * blockDim.x + threadIdx.x;
  if (idx >= HW) return;
  int k = idx / WW, n = idx % WW;
  int prod = (k - 160) * (n - 160);
  int r = prod % 320; if (r < 0) r += 320;
  float ang = -6.283185307179586f * (float)r / 320.0f;
  const float s = 0.05590169943749474f; // 1/sqrt(320)
  Fbf[idx] = pack_bf(cosf(ang) * s, sinf(ang) * s);
}

// ---------------- K0b: prepack conv weights (forward, A-operand) -----------
__global__ void k_prep(const float* __restrict__ ck, unsigned int* __restrict__ Wpk) {
  int idx = blockIdx.x * blockDim.x + threadIdx.x;
  if (idx >= 32 * 176) return;
  int o = idx / 176, kw = idx % 176;
  int ky = kw / 16, kx = kw % 16;
  unsigned int v = 0;
  if (kx <= 10) {
    const float* p = &ck[(o * 121 + ky * 11 + kx) * 2];
    v = pack_bf(p[0], p[1]);
  }
  Wpk[idx] = v;
}

// ---------------- K0c: prepack adjoint weights Wt[ch][kx][ky16][o32] -------
__global__ void k_prep2(const float* __restrict__ ck, unsigned short* __restrict__ Wt) {
  int idx = blockIdx.x * blockDim.x + threadIdx.x;
  if (idx >= 2 * 11 * 16 * 32) return;
  int o = idx & 31;
  int ky = (idx >> 5) & 15;
  int rest = idx >> 9;
  int kx = rest % 11, ch = rest / 11;
  unsigned short v = 0;
  if (ky <= 10) v = f2b(ck[(o * 121 + ky * 11 + kx) * 2 + ch]);
  Wt[idx] = v;
}

// ---------------- K0d: RBF lookup table, bf16, [-2,2], 257 entries ---------
__global__ void k_rbftab(const float* __restrict__ w, const float* __restrict__ mu,
                         const float* __restrict__ sigma, unsigned short* __restrict__ Tab) {
  int o = blockIdx.x;
  int e = threadIdx.x;
  if (e >= TABN + 1) return;
  float v = -2.0f + (float)e * (4.0f / (float)TABN);
  float sg = sigma[0];
  float nInv = -1.0f / (2.0f * sg * sg);
  float acc = 0.f;
  for (int i = 0; i < NK; i++) {
    float d = v - mu[i];
    acc += w[o * NK + i] * __expf(d * d * nInv);
  }
  Tab[o * 260 + e] = f2b(acc);
}

// ---------------- K2: conv(11x11) + RBF(table) via MFMA implicit GEMM ------
__global__ __launch_bounds__(256) void k_conv_rbf_mfma(
    const float* __restrict__ u_t, const unsigned int* __restrict__ Wpk,
    const unsigned short* __restrict__ Tab, unsigned short* __restrict__ fukT) {
  __shared__ unsigned int lW[32 * 180];       // 23040 B
  __shared__ unsigned int tIn[26 * 32];       // 3328 B
  __shared__ unsigned short tab[32 * 260];    // 16640 B
  int n = blockIdx.z;
  int y0 = blockIdx.y * 16, x0 = blockIdx.x * 16;
  int tid = threadIdx.x;
  for (int i = tid; i < 32 * 176; i += 256)
    lW[(i / 176) * 180 + (i % 176)] = Wpk[i];
  {
    const unsigned int* Ts = (const unsigned int*)Tab;
    unsigned int* Td = (unsigned int*)tab;
    for (int i = tid; i < 32 * 130; i += 256) Td[i] = Ts[i];
  }
  for (int i = tid; i < 26 * 32; i += 256) {
    int rr = i >> 5, cc = i & 31;
    unsigned int v = 0;
    if (cc < 26) {
      int py = y0 + rr - 5, px = x0 + cc - 5;
      if (py >= 0 && py < HP && px >= 0 && px < HP) {
        int uy = py - PADN; uy = uy < 0 ? -uy : (uy >= HH ? 2 * (HH - 1) - uy : uy);
        int ux = px - PADN; ux = ux < 0 ? -ux : (ux >= WW ? 2 * (WW - 1) - ux : ux);
        const float* up = &u_t[((n * HH + uy) * WW + ux) * 2];
        v = pack_bf(up[0], up[1]);
      }
    }
    tIn[i] = v;
  }
  __syncthreads();
  int lane = tid & 63, wave = tid >> 6;
  int m16 = lane & 15, kq = lane >> 4;
  const short* lWs = (const short*)lW;
  f32x4 acc[4][2] = {};
  for (int ky = 0; ky < 11; ky++) {
    bf16x8 af0 = *(const bf16x8*)&lWs[m16 * 360 + ky * 32 + kq * 8];
    bf16x8 af1 = *(const bf16x8*)&lWs[(m16 + 16) * 360 + ky * 32 + kq * 8];
    #pragma unroll
    for (int nt = 0; nt < 4; nt++) {
      int rr = wave * 4 + nt + ky;
      int c0 = rr * 32 + m16 + kq * 4;
      union { unsigned int u[4]; bf16x8 v; } bu;
      bu.u[0] = tIn[c0]; bu.u[1] = tIn[c0 + 1];
      bu.u[2] = tIn[c0 + 2]; bu.u[3] = tIn[c0 + 3];
      acc[nt][0] = MFMA16(af0, bu.v, acc[nt][0], 0, 0, 0);
      acc[nt][1] = MFMA16(af1, bu.v, acc[nt][1], 0, 0, 0);
    }
  }
  // RBF via table lookup + lerp. C layout: col=lane&15 (x), row=kq*4+r (o)
  const float tscale = (float)TABN / 4.0f;    // 64 per unit v
  #pragma unroll
  for (int nt = 0; nt < 4; nt++) {
    int Y = y0 + wave * 4 + nt;
    int X = x0 + m16;
    if (Y >= HP || X >= HP) continue;
    #pragma unroll
    for (int mt = 0; mt < 2; mt++) {
      u16x4 pk;
      #pragma unroll
      for (int r = 0; r < 4; r++) {
        float v = acc[nt][mt][r];
        int o = mt * 16 + kq * 4 + r;
        float t = (v + 2.0f) * tscale;
        t = fminf(fmaxf(t, 0.0f), 255.999f);
        int i0 = (int)t;
        float fr = t - (float)i0;
        float a = b2f(tab[o * 260 + i0]);
        float bv = b2f(tab[o * 260 + i0 + 1]);
        pk[r] = f2b(a + (bv - a) * fr);
      }
      *(u16x4*)&fukT[(((size_t)n * HP + Y) * HP + X) * 32 + mt * 16 + kq * 4] = pk;
    }
  }
}

// ---------------- K3: transposed conv via MFMA -----------------------------
__global__ __launch_bounds__(256) void k_convT_mfma(
    const unsigned short* __restrict__ fukT, const unsigned short* __restrict__ Wt,
    float* __restrict__ Ru) {
  __shared__ unsigned short rowBuf[42 * 32];
  __shared__ float accS[16 * 67];
  int n = blockIdx.z;
  int y0 = blockIdx.y * 16, x0 = blockIdx.x * 32;
  int tid = threadIdx.x;
  int lane = tid & 63, wave = tid >> 6;
  int ch = wave >> 1, xh = wave & 1;
  int m16 = lane & 15, kq = lane >> 4;
  bf16x8 afr[11];
  #pragma unroll
  for (int kx = 0; kx < 11; kx++)
    afr[kx] = *(const bf16x8*)&Wt[((ch * 11 + kx) * 16 + m16) * 32 + kq * 8];
  for (int i = tid; i < 16 * 67; i += 256) accS[i] = 0.f;
  int xl = xh * 16 + m16;
  for (int t = 0; t < 26; t++) {
    int r = y0 + 6 + t;
    __syncthreads();
    {
      const unsigned int* src = (const unsigned int*)&fukT[(((size_t)n * HP + r) * HP + x0 + 6) * 32];
      unsigned int* dst = (unsigned int*)rowBuf;
      for (int i = tid; i < 42 * 16; i += 256) dst[i] = src[i];
    }
    __syncthreads();
    f32x4 dacc = {};
    #pragma unroll
    for (int kx = 0; kx < 11; kx++) {
      bf16x8 bfrag = *(const bf16x8*)&rowBuf[(xl + 10 - kx) * 32 + kq * 8];
      dacc = MFMA16(afr[kx], bfrag, dacc, 0, 0, 0);
    }
    #pragma unroll
    for (int rg = 0; rg < 4; rg++) {
      int ky = kq * 4 + rg;
      int y = t + ky - 10;
      if (ky <= 10 && y >= 0 && y < 16)
        accS[y * 67 + xl * 2 + ch] += dacc[rg];
    }
  }
  __syncthreads();
  int chO = tid & 1, xO = (tid >> 1) & 31, yb = tid >> 6;
  #pragma unroll
  for (int q = 0; q < 4; q++) {
    int y = yb + q * 4;
    Ru[(((size_t)n * HH + y0 + y) * WW + x0 + xO) * 2 + chO] = accS[y * 67 + xO * 2 + chO];
  }
}

// ---------------- K4: X0 = u * coil_sens (complex), bf16 pairs -------------
__global__ void k_umul(const float* __restrict__ u_t, const float* __restrict__ cs,
                       unsigned int* __restrict__ X0) {
  int idx = blockIdx.x * blockDim.x + threadIdx.x;
  if (idx >= NCB * HW) return;
  int hw = idx % HW;
  int n = (idx / HW) / CC;
  float ur = u_t[(n * HW + hw) * 2], ui = u_t[(n * HW + hw) * 2 + 1];
  float cr = cs[idx * 2], ci = cs[idx * 2 + 1];
  X0[idx] = pack_bf(ur * cr - ui * ci, ur * ci + ui * cr);
}

// ---------------- K5: batched complex GEMM via bf16 MFMA (v2) --------------
__global__ __launch_bounds__(256) void k_gemm(
    const unsigned int* __restrict__ Abase, long aStride,
    unsigned int xorA1, unsigned int xorA2,
    const unsigned int* __restrict__ Bbase, long bStride, unsigned int xorB,
    unsigned int* __restrict__ OutB, int mode,
    const float* __restrict__ mask, const float* __restrict__ fdat) {
  __shared__ unsigned int lA[64 * 36];
  __shared__ unsigned int lB[32 * 68];
  int b = blockIdx.z;
  int i0 = blockIdx.y * 64, j0 = blockIdx.x * 64;
  const unsigned int* A = Abase + (size_t)b * aStride;
  const unsigned int* B = Bbase + (size_t)b * bStride;
  int tid = threadIdx.x;
  int lane = tid & 63, wave = tid >> 6;
  int wy = (wave >> 1) * 32, wx = (wave & 1) * 32;
  int m16 = lane & 15, kq = lane >> 4;
  f32x4 accR[2][2] = {}, accI[2][2] = {};
  int ar = tid >> 3;
  int ag = tid & 7;
  int bkc = tid >> 4;
  int bc = (tid & 15) * 4;
  uint4 pa0, pa1, pb0, pb1;
  pa0 = *(const uint4*)&A[(i0 + ar) * WW + ag * 4];
  pa1 = *(const uint4*)&A[(i0 + ar + 32) * WW + ag * 4];
  pb0 = *(const uint4*)&B[bkc * WW + j0 + bc];
  pb1 = *(const uint4*)&B[(bkc + 16) * WW + j0 + bc];
  for (int it = 0; it < 10; it++) {
    __syncthreads();
    *(uint4*)&lA[ar * 36 + ag * 4] = pa0;
    *(uint4*)&lA[(ar + 32) * 36 + ag * 4] = pa1;
    *(uint4*)&lB[bkc * 68 + bc] = pb0;
    *(uint4*)&lB[(bkc + 16) * 68 + bc] = pb1;
    __syncthreads();
    if (it < 9) {
      int kc0 = (it + 1) * 32;
      pa0 = *(const uint4*)&A[(i0 + ar) * WW + kc0 + ag * 4];
      pa1 = *(const uint4*)&A[(i0 + ar + 32) * WW + kc0 + ag * 4];
      pb0 = *(const uint4*)&B[(kc0 + bkc) * WW + j0 + bc];
      pb1 = *(const uint4*)&B[(kc0 + bkc + 16) * WW + j0 + bc];
    }
    #pragma unroll
    for (int s = 0; s < 2; s++) {
      bf16x8 a1[2], a2[2], bb[2];
      #pragma unroll
      for (int d = 0; d < 2; d++) {
        int row = wy + d * 16 + m16;
        uint4 p = *(const uint4*)&lA[row * 36 + s * 16 + kq * 4];
        union { unsigned int u[4]; bf16x8 v; } ua, ur2, ub;
        ua.u[0] = p.x ^ xorA1; ua.u[1] = p.y ^ xorA1;
        ua.u[2] = p.z ^ xorA1; ua.u[3] = p.w ^ xorA1;
        a1[d] = ua.v;
        ur2.u[0] = rot16(p.x) ^ xorA2; ur2.u[1] = rot16(p.y) ^ xorA2;
        ur2.u[2] = rot16(p.z) ^ xorA2; ur2.u[3] = rot16(p.w) ^ xorA2;
        a2[d] = ur2.v;
        int col = wx + d * 16 + m16;
        #pragma unroll
        for (int j2 = 0; j2 < 4; j2++)
          ub.u[j2] = lB[(s * 16 + kq * 4 + j2) * 68 + col] ^ xorB;
        bb[d] = ub.v;
      }
      #pragma unroll
      for (int di = 0; di < 2; di++)
        #pragma unroll
        for (int dj = 0; dj < 2; dj++) {
          accR[di][dj] = MFMA16(a1[di], bb[dj], accR[di][dj], 0, 0, 0);
          accI[di][dj] = MFMA16(a2[di], bb[dj], accI[di][dj], 0, 0, 0);
        }
    }
  }
  int n = b / CC;
  #pragma unroll
  for (int di = 0; di < 2; di++)
    #pragma unroll
    for (int dj = 0; dj < 2; dj++)
      #pragma unroll
      for (int r = 0; r < 4; r++) {
        int row = i0 + wy + di * 16 + kq * 4 + r;
        int col = j0 + wx + dj * 16 + m16;
        float vr = accR[di][dj][r], vi = accI[di][dj][r];
        size_t idx = (size_t)b * HW + row * WW + col;
        if (mode == 1) {
          float m = mask[n * HW + row * WW + col];
          vr = m * (vr - fdat[idx * 2]);
          vi = m * (vi - fdat[idx * 2 + 1]);
        }
        OutB[idx] = pack_bf(vr, vi);
      }
}

// ---------------- K6: coil-combine with conj(sens), bf16-pair input --------
__global__ void k_coilsum(const unsigned int* __restrict__ Z, const float* __restrict__ cs,
                          float* __restrict__ At) {
  int idx = blockIdx.x * blockDim.x + threadIdx.x;
  if (idx >= NN * HW) return;
  int n = idx / HW, hw = idx % HW;
  float ar = 0.f, ai = 0.f;
  for (int c = 0; c < CC; c++) {
    size_t zi = (size_t)(n * CC + c) * HW + hw;
    unsigned int p = Z[zi];
    float zr = b2f((unsigned short)(p & 0xffff));
    float zim = b2f((unsigned short)(p >> 16));
    float crr = cs[zi * 2], cii = cs[zi * 2 + 1];
    ar += zr * crr + zim * cii;
    ai += zim * crr - zr * cii;
  }
  At[idx * 2] = ar;
  At[idx * 2 + 1] = ai;
}

// ---------------- K7: out = u - Ru/FF - lamb*At ----------------------------
__global__ void k_final(const float* __restrict__ u_t, const float* __restrict__ Ru,
                        const float* __restrict__ At, const float* __restrict__ lamb,
                        float* __restrict__ out) {
  int idx = blockIdx.x * blockDim.x + threadIdx.x;
  if (idx >= NN * HW * 2) return;
  out[idx] = u_t[idx] - Ru[idx] * (1.0f / (float)FF) - lamb[0] * At[idx];
}

extern "C" void kernel_launch(void* const* d_in, const int* in_sizes, int n_in,
                              void* d_out, int out_size, void* d_ws, size_t ws_size,
                              hipStream_t stream) {
  const float* u_t   = (const float*)d_in[0];
  const float* fdat  = (const float*)d_in[1];
  const float* cs    = (const float*)d_in[2];
  const float* mask  = (const float*)d_in[3];
  const float* ck    = (const float*)d_in[4];
  const float* w     = (const float*)d_in[5];
  const float* mu    = (const float*)d_in[6];
  const float* sigma = (const float*)d_in[7];
  const float* lamb  = (const float*)d_in[8];
  float* out = (float*)d_out;

  // ws layout (u32 words):
  //  Fbf @0          102400
  //  Wpk @102400     5760
  //  Wt  @108160     5632
  //  Tab @113792     4160
  //  At  @117952     819200
  //  Ru  @937152     819200
  //  big @1756352    12288000  (conv phase: fukT [7485696 w]; DC: P | Q)
  unsigned int* wsw = (unsigned int*)d_ws;
  unsigned int* Fbf = wsw;
  unsigned int* Wpk = wsw + 102400;
  unsigned short* Wt = (unsigned short*)(wsw + 108160);
  unsigned short* Tab = (unsigned short*)(wsw + 113792);
  float* At = (float*)(wsw + 117952);
  float* Ru = (float*)(wsw + 937152);
  unsigned int* big = wsw + 1756352;
  unsigned short* fukT = (unsigned short*)big;
  unsigned int* P = big;
  unsigned int* Q = big + 6144000;

  k_dft<<<(HW + 255) / 256, 256, 0, stream>>>(Fbf);
  k_prep<<<(32 * 176 + 255) / 256, 256, 0, stream>>>(ck, Wpk);
  k_prep2<<<(2 * 11 * 16 * 32 + 255) / 256, 256, 0, stream>>>(ck, Wt);
  k_rbftab<<<32, 320, 0, stream>>>(w, mu, sigma, Tab);
  k_conv_rbf_mfma<<<dim3(22, 22, NN), 256, 0, stream>>>(u_t, Wpk, Tab, fukT);
  k_convT_mfma<<<dim3(10, 20, NN), 256, 0, stream>>>(fukT, Wt, Ru);
  k_umul<<<(NCB * HW + 255) / 256, 256, 0, stream>>>(u_t, cs, P);
  k_gemm<<<dim3(5, 5, NCB), 256, 0, stream>>>(Fbf, 0L, 0x80000000u, 0u,
                                              P, (long)HW, 0u,
                                              Q, 0, nullptr, nullptr);
  k_gemm<<<dim3(5, 5, NCB), 256, 0, stream>>>(Q, (long)HW, 0x80000000u, 0u,
                                              Fbf, 0L, 0u,
                                              P, 1, mask, fdat);
  k_gemm<<<dim3(5, 5, NCB), 256, 0, stream>>>(Fbf, 0L, 0u, 0x00008000u,
                                              P, (long)HW, 0u,
                                              Q, 0, nullptr, nullptr);
  k_gemm<<<dim3(5, 5, NCB), 256, 0, stream>>>(Q, (long)HW, 0x80000000u, 0u,
                                              Fbf, 0L, 0x80000000u,
                                              P, 0, nullptr, nullptr);
  k_coilsum<<<(NN * HW + 255) / 256, 256, 0, stream>>>(P, cs, At);
  k_final<<<(NN * HW * 2 + 255) / 256, 256, 0, stream>>>(u_t, Ru, At, lamb, out);
}